// Round 5
// baseline (160.655 us; speedup 1.0000x reference)
//
#include <hip/hip_runtime.h>
#include <hip/hip_bf16.h>

typedef __attribute__((ext_vector_type(8))) short bf16x8;
typedef __attribute__((ext_vector_type(4))) float f32x4;
typedef __attribute__((ext_vector_type(2))) _Float16 h2;
typedef __attribute__((ext_vector_type(8))) _Float16 h8;
typedef unsigned int uint;

constexpr int NPTS = 8192;
constexpr int BPTS = 16384;     // B*N
constexpr int KNN  = 16;

// async global->LDS, 16B per lane; LDS dest is wave-uniform base + lane*16.
__device__ __forceinline__ void gload16(const void* g, void* l) {
    __builtin_amdgcn_global_load_lds(
        (const __attribute__((address_space(1))) unsigned int*)g,
        (__attribute__((address_space(3))) unsigned int*)l, 16, 0, 0);
}

__device__ __forceinline__ uint packbf2(float a, float b) {
    union { __hip_bfloat16 h; unsigned short u; } ua, ub;
    ua.h = __float2bfloat16(a); ub.h = __float2bfloat16(b);
    return (uint)ua.u | ((uint)ub.u << 16);
}

// ---------------------------------------------------------------------------
// bf16 MFMA GEMM: C[M,N] = A[M,KD] @ Bt[N,KD]^T + bias (+res)
// BM=128, BN=64 tile, BK=64, 4 waves (2x2 of 64x32), 16x16x32 MFMA, fp32 acc.
// XOR-swizzled LDS (8 slots/row), staged via global_load_lds with the
// inverse swizzle applied to the per-lane global address.
// OUTT: 0 = f32, 1 = bf16, 2 = f16
// ---------------------------------------------------------------------------
template<int KD, bool RES, int OUTT, bool LRELU>
__global__ __launch_bounds__(256) void gemm_mfma(
    const __hip_bfloat16* __restrict__ A,   // [M, KD]
    const __hip_bfloat16* __restrict__ Bt,  // [N, KD]
    const float* __restrict__ b0, const float* __restrict__ b1,
    const float* __restrict__ b2,
    const __hip_bfloat16* __restrict__ res, // [M, N] or null
    void* __restrict__ Cout, int M, int N)
{
    __shared__ __align__(16) __hip_bfloat16 As[128 * 64];   // 16 KB
    __shared__ __align__(16) __hip_bfloat16 Bs[64 * 64];    // 8 KB

    const int tid  = threadIdx.x;
    const int lane = tid & 63;
    const int wid  = tid >> 6;
    const int wm   = (wid >> 1) * 64;
    const int wn   = (wid & 1) * 32;
    const int bm   = blockIdx.y * 128;
    const int bn   = blockIdx.x * 64;

    const int srow8 = lane >> 3;
    const int sslot = (lane & 7) ^ srow8;
    const int r = lane & 15;
    const int g = lane >> 4;

    f32x4 acc[4][2] = {};

    for (int k0 = 0; k0 < KD; k0 += 64) {
        #pragma unroll
        for (int p = 0; p < 4; ++p) {
            const int rowA = p * 32 + wid * 8 + srow8;
            gload16(&A[(size_t)(bm + rowA) * KD + k0 + sslot * 8],
                    (char*)As + (p * 32 + wid * 8) * 128);
        }
        #pragma unroll
        for (int p = 0; p < 2; ++p) {
            const int rowB = p * 32 + wid * 8 + srow8;
            gload16(&Bt[(size_t)(bn + rowB) * KD + k0 + sslot * 8],
                    (char*)Bs + (p * 32 + wid * 8) * 128);
        }
        __syncthreads();

        bf16x8 af[2][4], bfr[2][2];
        #pragma unroll
        for (int s = 0; s < 2; ++s) {
            const int physA = (s * 4 + g) ^ (r & 7);
            #pragma unroll
            for (int mi = 0; mi < 4; ++mi)
                af[s][mi] = *(const bf16x8*)((const char*)As + (wm + mi * 16 + r) * 128 + physA * 16);
            #pragma unroll
            for (int ni = 0; ni < 2; ++ni)
                bfr[s][ni] = *(const bf16x8*)((const char*)Bs + (wn + ni * 16 + r) * 128 + physA * 16);
        }
        #pragma unroll
        for (int s = 0; s < 2; ++s)
            #pragma unroll
            for (int mi = 0; mi < 4; ++mi)
                #pragma unroll
                for (int ni = 0; ni < 2; ++ni)
                    acc[mi][ni] = __builtin_amdgcn_mfma_f32_16x16x32_bf16(
                        af[s][mi], bfr[s][ni], acc[mi][ni], 0, 0, 0);
        __syncthreads();
    }

    #pragma unroll
    for (int ni = 0; ni < 2; ++ni) {
        const int col = bn + wn + ni * 16 + r;
        const float* bsel = (col < 256) ? b0 : (col < 512 ? b1 : b2);
        const float bias = bsel[col & 255];
        #pragma unroll
        for (int mi = 0; mi < 4; ++mi) {
            #pragma unroll
            for (int q = 0; q < 4; ++q) {
                const int row = bm + wm + mi * 16 + g * 4 + q;
                float v = acc[mi][ni][q] + bias;
                if (RES)  v += __bfloat162float(res[(size_t)row * N + col]);
                if (LRELU) v = v > 0.f ? v : 0.01f * v;
                if (OUTT == 0)      ((float*)Cout)[(size_t)row * N + col] = v;
                else if (OUTT == 1) ((__hip_bfloat16*)Cout)[(size_t)row * N + col] = __float2bfloat16(v);
                else                ((_Float16*)Cout)[(size_t)row * N + col] = (_Float16)v;
            }
        }
    }
}

// ---------------------------------------------------------------------------
// prep: weights fp32[K][N] -> bf16[N][K]; features -> bf16; Wp/bp -> f16 rows.
// ---------------------------------------------------------------------------
__global__ __launch_bounds__(256) void prep_kernel(
    const float* __restrict__ W_in, const float* __restrict__ Wq,
    const float* __restrict__ Wk,  const float* __restrict__ Wv,
    const float* __restrict__ Wo,  const float* __restrict__ W_out,
    const float* __restrict__ features,
    const float* __restrict__ Wp,  const float* __restrict__ bp,
    __hip_bfloat16* __restrict__ WtIn,  __hip_bfloat16* __restrict__ WtQKV,
    __hip_bfloat16* __restrict__ WtO,   __hip_bfloat16* __restrict__ WtOut,
    __hip_bfloat16* __restrict__ featb, _Float16* __restrict__ Wpb)
{
    const int b = blockIdx.x;
    if (b < 592) {
        const float* srcs[10] = {W_in, Wq, Wk, Wv, Wq + 65536, Wk + 65536,
                                 Wv + 65536, Wo, Wo + 65536, W_out};
        __hip_bfloat16* dsts[10] = {
            WtIn, WtQKV, WtQKV + 65536, WtQKV + 131072,
            WtQKV + 196608, WtQKV + 262144, WtQKV + 327680,
            WtO, WtO + 65536, WtOut};
        const int Ks[10]    = {64,256,256,256,256,256,256,256,256,256};
        const int start[10] = {0,16,80,144,208,272,336,400,464,528};
        int j = 0;
        #pragma unroll
        for (int i = 1; i < 10; ++i) if (b >= start[i]) j = i;
        const int t  = b - start[j];
        const int Kd = Ks[j];
        const int ntk = Kd >> 5;
        const int tn = t / ntk;
        const int tk = t - tn * ntk;

        __shared__ float s[32][33];
        const int tx = threadIdx.x & 31, ty = threadIdx.x >> 5;
        const float* src = srcs[j];
        #pragma unroll
        for (int i = 0; i < 4; ++i)
            s[ty + i * 8][tx] = src[(size_t)(tk * 32 + ty + i * 8) * 256 + tn * 32 + tx];
        __syncthreads();
        __hip_bfloat16* dst = dsts[j];
        #pragma unroll
        for (int i = 0; i < 4; ++i)
            dst[(size_t)(tn * 32 + ty + i * 8) * Kd + tk * 32 + tx] =
                __float2bfloat16(s[tx][ty + i * 8]);
    } else if (b < 1616) {
        const int i = (b - 592) * 1024 + threadIdx.x * 4;
        const float4 v = *(const float4*)&features[i];
        __hip_bfloat16 tmp[4] = {__float2bfloat16(v.x), __float2bfloat16(v.y),
                                 __float2bfloat16(v.z), __float2bfloat16(v.w)};
        *(uint2*)&featb[i] = *(const uint2*)tmp;
    } else {
        // Wp (L,3,256) + bp (L,256) -> Wpb[l][4][256] f16 (row 3 = bp)
        const int e8 = threadIdx.x * 8;
        const int l  = e8 >> 10;
        const int rr = (e8 >> 8) & 3;
        const int c  = e8 & 255;
        const float* src = (rr < 3) ? (Wp + (size_t)l * 768 + rr * 256 + c)
                                    : (bp + (size_t)l * 256 + c);
        const float4 f0 = ((const float4*)src)[0];
        const float4 f1 = ((const float4*)src)[1];
        _Float16 t[8] = {(_Float16)f0.x, (_Float16)f0.y, (_Float16)f0.z, (_Float16)f0.w,
                         (_Float16)f1.x, (_Float16)f1.y, (_Float16)f1.z, (_Float16)f1.w};
        *(uint4*)&Wpb[(size_t)l * 1024 + rr * 256 + c] = *(const uint4*)t;
    }
}

// ---------------------------------------------------------------------------
// fuse layer-1 qkv weights through W_in:
//   WcT[cc][r] = (W_in @ Wqkv1)[r][cc]  (bf16, transposed for the GEMM)
//   bc[cc]     = b_in . Wqkv1[:,cc] + bqkv1[cc]
// 24 blocks x 256 threads; block covers 32 combined cols.
// ---------------------------------------------------------------------------
__global__ __launch_bounds__(256) void fuse_w1_kernel(
    const float* __restrict__ W_in, const float* __restrict__ b_in,
    const float* __restrict__ Wq, const float* __restrict__ bq,
    const float* __restrict__ Wk, const float* __restrict__ bk,
    const float* __restrict__ Wv, const float* __restrict__ bv,
    __hip_bfloat16* __restrict__ WcT, float* __restrict__ bc)
{
    __shared__ float ws[256][32];
    const int c0  = blockIdx.x * 32;
    const int seg = c0 >> 8;            // 0=q,1=k,2=v
    const int cs  = c0 & 255;
    const float* Wsrc = seg == 0 ? Wq : (seg == 1 ? Wk : Wv);
    const float* bsrc = seg == 0 ? bq : (seg == 1 ? bk : bv);
    const int tx = threadIdx.x & 31, ty = threadIdx.x >> 5;  // ty 0..7

    #pragma unroll 4
    for (int i = 0; i < 32; ++i) {
        const int k = i * 8 + ty;
        ws[k][tx] = Wsrc[(size_t)k * 256 + cs + tx];
    }
    __syncthreads();

    #pragma unroll
    for (int rr = 0; rr < 8; ++rr) {
        const int r = rr * 8 + ty;
        float acc = 0.f;
        for (int k = 0; k < 256; ++k)
            acc += W_in[(size_t)r * 256 + k] * ws[k][tx];
        WcT[(size_t)(c0 + tx) * 64 + r] = __float2bfloat16(acc);
    }
    if (ty == 0) {
        float acc = 0.f;
        for (int k = 0; k < 256; ++k)
            acc += b_in[k] * ws[k][tx];
        bc[c0 + tx] = acc + bsrc[cs + tx];
    }
}

// ---------------------------------------------------------------------------
// KNN attention, f16 qkv, folded positional encoding, 4 points / 512 threads.
// ---------------------------------------------------------------------------
__global__ __launch_bounds__(512) void knn_attn_kernel(
    const float* __restrict__ xyz,        // [BPTS,3]
    const int*   __restrict__ idx,        // [BPTS,KNN]
    const _Float16* __restrict__ qkv,     // [BPTS,768] = q|k|v
    const _Float16* __restrict__ Wpb,     // [4][256]  (Wp rows + bp)
    __hip_bfloat16* __restrict__ o)       // [BPTS,256]
{
    const int tid = threadIdx.x;
    const int pt  = tid >> 7;            // 0..3
    const int lt  = tid & 127;
    const int p0  = blockIdx.x * 4;
    const int p   = p0 + pt;
    const int h   = lt >> 4;
    const int k   = lt & 15;

    __shared__ float s_rel[4][KNN][3];
    __shared__ float s_wq[4][8][4];
    __shared__ float s_attn[4][8][KNN];
    __shared__ float s_arel[4][8][3];
    __shared__ __align__(16) _Float16 v_lds[4][KNN][256];  // 32 KB

    // --- QK loads (oldest in flight) ---
    const int jrow = ((p >> 13) << 13) + idx[p * KNN + k];
    const h8* qp = (const h8*)(qkv + (size_t)p * 768 + h * 32);
    const h8* kp = (const h8*)(qkv + (size_t)jrow * 768 + 256 + h * 32);
    const h8 q0 = qp[0], q1 = qp[1];
    const h8 k0 = kp[0], k1 = kp[1];

    // --- async V staging: 64 rows x 512B; each of 8 waves covers 8 rows ---
    {
        const int w = tid >> 6, ln = tid & 63;
        #pragma unroll
        for (int c = 0; c < 4; ++c) {
            const int grE = w * 8 + c * 2;               // even row id 0..62
            const int gr  = grE + (ln >> 5);
            const int ptw = grE >> 4, kkE = grE & 15;
            const int pg  = p0 + (gr >> 4);
            const int jr  = ((pg >> 13) << 13) + idx[pg * KNN + (gr & 15)];
            gload16(qkv + (size_t)jr * 768 + 512 + (ln & 31) * 8,
                    (char*)&v_lds[ptw][kkE][0]);
        }
    }

    // --- side computations while loads fly ---
    if (tid < 64) {
        const int pp = tid >> 4, kk = tid & 15;
        const int pg = p0 + pp;
        const int jr = ((pg >> 13) << 13) + idx[pg * KNN + kk];
        s_rel[pp][kk][0] = xyz[pg * 3 + 0] - xyz[jr * 3 + 0];
        s_rel[pp][kk][1] = xyz[pg * 3 + 1] - xyz[jr * 3 + 1];
        s_rel[pp][kk][2] = xyz[pg * 3 + 2] - xyz[jr * 3 + 2];
    } else if (tid < 192) {
        const int t2 = tid - 64;
        const int pp = t2 >> 5, hh = (t2 >> 2) & 7, j = t2 & 3;
        const h8* qr = (const h8*)(qkv + (size_t)(p0 + pp) * 768 + hh * 32);
        const h8* wr = (const h8*)(Wpb + j * 256 + hh * 32);
        const h8 a0 = qr[0], a1 = qr[1], b0 = wr[0], b1 = wr[1];
        float acc = 0.f;
        #pragma unroll
        for (int i = 0; i < 4; ++i)
            acc = __builtin_amdgcn_fdot2(((const h2*)&a0)[i], ((const h2*)&b0)[i], acc, false);
        #pragma unroll
        for (int i = 0; i < 4; ++i)
            acc = __builtin_amdgcn_fdot2(((const h2*)&a1)[i], ((const h2*)&b1)[i], acc, false);
        s_wq[pp][hh][j] = acc;
    }

    // --- QK dot (fdot2) ---
    float dot = 0.f;
    #pragma unroll
    for (int i = 0; i < 4; ++i)
        dot = __builtin_amdgcn_fdot2(((const h2*)&q0)[i], ((const h2*)&k0)[i], dot, false);
    #pragma unroll
    for (int i = 0; i < 4; ++i)
        dot = __builtin_amdgcn_fdot2(((const h2*)&q1)[i], ((const h2*)&k1)[i], dot, false);
    __syncthreads();

    // --- logit + softmax + arel ---
    const float r0 = s_rel[pt][k][0], r1 = s_rel[pt][k][1], r2 = s_rel[pt][k][2];
    const float logit = (dot + r0 * s_wq[pt][h][0] + r1 * s_wq[pt][h][1]
                             + r2 * s_wq[pt][h][2] + s_wq[pt][h][3])
                        * 0.1767766952966369f;
    float mx = logit;
    #pragma unroll
    for (int off = 8; off >= 1; off >>= 1)
        mx = fmaxf(mx, __shfl_xor(mx, off, 16));
    const float e = __expf(logit - mx);
    float den = e;
    #pragma unroll
    for (int off = 8; off >= 1; off >>= 1)
        den += __shfl_xor(den, off, 16);
    const float attn = e / den;
    s_attn[pt][h][k] = attn;

    float a0 = attn * r0, a1 = attn * r1, a2 = attn * r2;
    #pragma unroll
    for (int off = 8; off >= 1; off >>= 1) {
        a0 += __shfl_xor(a0, off, 16);
        a1 += __shfl_xor(a1, off, 16);
        a2 += __shfl_xor(a2, off, 16);
    }
    if (k == 0) {
        s_arel[pt][h][0] = a0;
        s_arel[pt][h][1] = a1;
        s_arel[pt][h][2] = a2;
    }
    __syncthreads();   // drains async V stage too

    // --- PV: thread = (pt, channel pair); head of ch == h ---
    {
        const int ch = lt * 2;
        float ax = 0.f, ay = 0.f;
        #pragma unroll
        for (int kk = 0; kk < KNN; ++kk) {
            const float a = s_attn[pt][h][kk];
            const h2 vf = *(const h2*)&v_lds[pt][kk][ch];
            ax += a * (float)vf.x;
            ay += a * (float)vf.y;
        }
        const h2 w0 = *(const h2*)&Wpb[ch];
        const h2 w1 = *(const h2*)&Wpb[256 + ch];
        const h2 w2 = *(const h2*)&Wpb[512 + ch];
        const h2 w3 = *(const h2*)&Wpb[768 + ch];
        const float g0 = s_arel[pt][h][0], g1 = s_arel[pt][h][1], g2 = s_arel[pt][h][2];
        ax += g0 * (float)w0.x + g1 * (float)w1.x + g2 * (float)w2.x + (float)w3.x;
        ay += g0 * (float)w0.y + g1 * (float)w1.y + g2 * (float)w2.y + (float)w3.y;
        *(uint*)&o[(size_t)p * 256 + ch] = packbf2(ax, ay);
    }
}

// ---------------------------------------------------------------------------
extern "C" void kernel_launch(void* const* d_in, const int* in_sizes, int n_in,
                              void* d_out, int out_size, void* d_ws, size_t ws_size,
                              hipStream_t stream)
{
    const float* xyzs     = (const float*)d_in[0];
    const float* features = (const float*)d_in[1];
    const int*   k_graph  = (const int*)  d_in[2];
    const float* W_in     = (const float*)d_in[3];
    const float* b_in     = (const float*)d_in[4];
    const float* Wq       = (const float*)d_in[5];
    const float* bq       = (const float*)d_in[6];
    const float* Wk       = (const float*)d_in[7];
    const float* bk       = (const float*)d_in[8];
    const float* Wv       = (const float*)d_in[9];
    const float* bv       = (const float*)d_in[10];
    const float* Wp       = (const float*)d_in[11];
    const float* bp       = (const float*)d_in[12];
    const float* Wo       = (const float*)d_in[13];
    const float* bo       = (const float*)d_in[14];
    const float* W_out    = (const float*)d_in[15];
    const float* b_out    = (const float*)d_in[16];

    __hip_bfloat16* featb = (__hip_bfloat16*)d_ws;       // 16384*64
    __hip_bfloat16* f     = featb + 1048576;             // 16384*256
    _Float16*       qkv   = (_Float16*)(f + 4194304);    // 16384*768 (f16)
    __hip_bfloat16* ob    = (__hip_bfloat16*)(qkv + 12582912);  // 16384*256
    __hip_bfloat16* WtIn  = ob + 4194304;                // 256*64
    __hip_bfloat16* WtQKV = WtIn + 16384;                // 2*768*256
    __hip_bfloat16* WtO   = WtQKV + 393216;              // 2*256*256
    __hip_bfloat16* WtOut = WtO + 131072;                // 256*256
    _Float16*       Wpb   = (_Float16*)(WtOut + 65536);  // 2*1024
    __hip_bfloat16* WcT   = (__hip_bfloat16*)(Wpb + 2048);  // 768*64
    float*          bc    = (float*)(WcT + 49152);       // 768

    prep_kernel<<<1617, 256, 0, stream>>>(W_in, Wq, Wk, Wv, Wo, W_out, features,
                                          Wp, bp, WtIn, WtQKV, WtO, WtOut,
                                          featb, Wpb);
    fuse_w1_kernel<<<24, 256, 0, stream>>>(W_in, b_in, Wq, bq, Wk, bk, Wv, bv,
                                           WcT, bc);

    // f = features @ W_in + b_in   (needed for layer-1 residual)
    gemm_mfma<64, false, 1, false><<<dim3(4, 128), 256, 0, stream>>>(
        featb, WtIn, b_in, b_in, b_in, nullptr, f, BPTS, 256);

    // layer 1 qkv: features @ (W_in.Wqkv1) + bc   (K=64)
    gemm_mfma<64, false, 2, false><<<dim3(12, 128), 256, 0, stream>>>(
        featb, WcT, bc, bc + 256, bc + 512, nullptr, qkv, BPTS, 768);

    for (int l = 0; l < 2; ++l) {
        if (l == 1) {
            gemm_mfma<256, false, 2, false><<<dim3(12, 128), 256, 0, stream>>>(
                f, WtQKV + 196608,
                bq + 256, bk + 256, bv + 256, nullptr, qkv, BPTS, 768);
        }

        knn_attn_kernel<<<dim3(BPTS / 4), 512, 0, stream>>>(
            xyzs, k_graph, qkv, Wpb + (size_t)l * 1024, ob);

        // f = ob @ Wo + bo + f
        gemm_mfma<256, true, 1, false><<<dim3(4, 128), 256, 0, stream>>>(
            ob, WtO + (size_t)l * 65536,
            bo + l * 256, bo + l * 256, bo + l * 256, f, f, BPTS, 256);
    }

    // out = leaky_relu(f @ W_out + b_out), fp32
    gemm_mfma<256, false, 0, true><<<dim3(4, 128), 256, 0, stream>>>(
        f, WtOut, b_out, b_out, b_out, nullptr, (float*)d_out, BPTS, 256);
}

// Round 6
// 139.407 us; speedup vs baseline: 1.1524x; 1.1524x over previous
//
#include <hip/hip_runtime.h>
#include <hip/hip_bf16.h>

typedef __attribute__((ext_vector_type(8))) short bf16x8;
typedef __attribute__((ext_vector_type(4))) float f32x4;
typedef __attribute__((ext_vector_type(2))) _Float16 h2;
typedef __attribute__((ext_vector_type(8))) _Float16 h8;
typedef unsigned int uint;

constexpr int NPTS = 8192;
constexpr int BPTS = 16384;     // B*N
constexpr int KNN  = 16;

// async global->LDS, 16B per lane; LDS dest is wave-uniform base + lane*16.
__device__ __forceinline__ void gload16(const void* g, void* l) {
    __builtin_amdgcn_global_load_lds(
        (const __attribute__((address_space(1))) unsigned int*)g,
        (__attribute__((address_space(3))) unsigned int*)l, 16, 0, 0);
}

__device__ __forceinline__ uint packbf2(float a, float b) {
    union { __hip_bfloat16 h; unsigned short u; } ua, ub;
    ua.h = __float2bfloat16(a); ub.h = __float2bfloat16(b);
    return (uint)ua.u | ((uint)ub.u << 16);
}

// ---------------------------------------------------------------------------
// bf16 MFMA GEMM: C[M,N] = A[M,KD] @ Bt[N,KD]^T (+bias)(+res)(+lrelu)
// BM=128, BN template (128 main / 64 for tiny fuse GEMM), BK=64, 4 waves,
// 16x16x32 MFMA, fp32 acc, XOR-swizzled LDS staged via global_load_lds.
// OUTT: 0 = f32, 1 = bf16, 2 = f16
// ---------------------------------------------------------------------------
template<int KD, bool RES, int OUTT, bool LRELU, int BN = 128, bool BIAS = true>
__global__ __launch_bounds__(256) void gemm_mfma(
    const __hip_bfloat16* __restrict__ A,   // [M, KD]
    const __hip_bfloat16* __restrict__ Bt,  // [N, KD]
    const float* __restrict__ b0, const float* __restrict__ b1,
    const float* __restrict__ b2,
    const __hip_bfloat16* __restrict__ res, // [M, N] or null
    void* __restrict__ Cout, int M, int N)
{
    constexpr int WN = BN / 2;        // per-wave N extent
    constexpr int NB = WN / 16;       // 4 (BN=128) or 2 (BN=64)

    __shared__ __align__(16) __hip_bfloat16 As[128 * 64];   // 16 KB
    __shared__ __align__(16) __hip_bfloat16 Bs[BN * 64];

    const int tid  = threadIdx.x;
    const int lane = tid & 63;
    const int wid  = tid >> 6;
    const int wm   = (wid >> 1) * 64;
    const int wn   = (wid & 1) * WN;
    const int bm   = blockIdx.y * 128;
    const int bn   = blockIdx.x * BN;

    const int srow8 = lane >> 3;
    const int sslot = (lane & 7) ^ srow8;
    const int r = lane & 15;
    const int g = lane >> 4;

    f32x4 acc[4][NB] = {};

    for (int k0 = 0; k0 < KD; k0 += 64) {
        #pragma unroll
        for (int p = 0; p < 4; ++p) {
            const int rowA = p * 32 + wid * 8 + srow8;
            gload16(&A[(size_t)(bm + rowA) * KD + k0 + sslot * 8],
                    (char*)As + (p * 32 + wid * 8) * 128);
        }
        #pragma unroll
        for (int p = 0; p < BN / 32; ++p) {
            const int rowB = p * 32 + wid * 8 + srow8;
            gload16(&Bt[(size_t)(bn + rowB) * KD + k0 + sslot * 8],
                    (char*)Bs + (p * 32 + wid * 8) * 128);
        }
        __syncthreads();

        bf16x8 af[2][4], bfr[2][NB];
        #pragma unroll
        for (int s = 0; s < 2; ++s) {
            const int physA = (s * 4 + g) ^ (r & 7);
            #pragma unroll
            for (int mi = 0; mi < 4; ++mi)
                af[s][mi] = *(const bf16x8*)((const char*)As + (wm + mi * 16 + r) * 128 + physA * 16);
            #pragma unroll
            for (int ni = 0; ni < NB; ++ni)
                bfr[s][ni] = *(const bf16x8*)((const char*)Bs + (wn + ni * 16 + r) * 128 + physA * 16);
        }
        #pragma unroll
        for (int s = 0; s < 2; ++s)
            #pragma unroll
            for (int mi = 0; mi < 4; ++mi)
                #pragma unroll
                for (int ni = 0; ni < NB; ++ni)
                    acc[mi][ni] = __builtin_amdgcn_mfma_f32_16x16x32_bf16(
                        af[s][mi], bfr[s][ni], acc[mi][ni], 0, 0, 0);
        __syncthreads();
    }

    #pragma unroll
    for (int ni = 0; ni < NB; ++ni) {
        const int col = bn + wn + ni * 16 + r;
        float bias = 0.f;
        if (BIAS) {
            const float* bsel = (col < 256) ? b0 : (col < 512 ? b1 : b2);
            bias = bsel[col & 255];
        }
        #pragma unroll
        for (int mi = 0; mi < 4; ++mi) {
            #pragma unroll
            for (int q = 0; q < 4; ++q) {
                const int row = bm + wm + mi * 16 + g * 4 + q;
                float v = acc[mi][ni][q] + bias;
                if (RES)  v += __bfloat162float(res[(size_t)row * N + col]);
                if (LRELU) v = v > 0.f ? v : 0.01f * v;
                if (OUTT == 0)      ((float*)Cout)[(size_t)row * N + col] = v;
                else if (OUTT == 1) ((__hip_bfloat16*)Cout)[(size_t)row * N + col] = __float2bfloat16(v);
                else                ((_Float16*)Cout)[(size_t)row * N + col] = (_Float16)v;
            }
        }
    }
}

// ---------------------------------------------------------------------------
// prep: weights fp32[K][N] -> bf16[N][K]; features -> bf16; Wp/bp -> f16;
// W_in -> bf16 row-major copy (for the fused-weight GEMM's B operand).
// ---------------------------------------------------------------------------
__global__ __launch_bounds__(256) void prep_kernel(
    const float* __restrict__ W_in, const float* __restrict__ Wq,
    const float* __restrict__ Wk,  const float* __restrict__ Wv,
    const float* __restrict__ Wo,  const float* __restrict__ W_out,
    const float* __restrict__ features,
    const float* __restrict__ Wp,  const float* __restrict__ bp,
    __hip_bfloat16* __restrict__ WtIn,  __hip_bfloat16* __restrict__ WtQKV,
    __hip_bfloat16* __restrict__ WtO,   __hip_bfloat16* __restrict__ WtOut,
    __hip_bfloat16* __restrict__ featb, _Float16* __restrict__ Wpb,
    __hip_bfloat16* __restrict__ WinB)
{
    const int b = blockIdx.x;
    if (b < 592) {
        const float* srcs[10] = {W_in, Wq, Wk, Wv, Wq + 65536, Wk + 65536,
                                 Wv + 65536, Wo, Wo + 65536, W_out};
        __hip_bfloat16* dsts[10] = {
            WtIn, WtQKV, WtQKV + 65536, WtQKV + 131072,
            WtQKV + 196608, WtQKV + 262144, WtQKV + 327680,
            WtO, WtO + 65536, WtOut};
        const int Ks[10]    = {64,256,256,256,256,256,256,256,256,256};
        const int start[10] = {0,16,80,144,208,272,336,400,464,528};
        int j = 0;
        #pragma unroll
        for (int i = 1; i < 10; ++i) if (b >= start[i]) j = i;
        const int t  = b - start[j];
        const int Kd = Ks[j];
        const int ntk = Kd >> 5;
        const int tn = t / ntk;
        const int tk = t - tn * ntk;

        __shared__ float s[32][33];
        const int tx = threadIdx.x & 31, ty = threadIdx.x >> 5;
        const float* src = srcs[j];
        #pragma unroll
        for (int i = 0; i < 4; ++i)
            s[ty + i * 8][tx] = src[(size_t)(tk * 32 + ty + i * 8) * 256 + tn * 32 + tx];
        __syncthreads();
        __hip_bfloat16* dst = dsts[j];
        #pragma unroll
        for (int i = 0; i < 4; ++i)
            dst[(size_t)(tn * 32 + ty + i * 8) * Kd + tk * 32 + tx] =
                __float2bfloat16(s[tx][ty + i * 8]);
    } else if (b < 1616) {
        const int i = (b - 592) * 1024 + threadIdx.x * 4;
        const float4 v = *(const float4*)&features[i];
        __hip_bfloat16 tmp[4] = {__float2bfloat16(v.x), __float2bfloat16(v.y),
                                 __float2bfloat16(v.z), __float2bfloat16(v.w)};
        *(uint2*)&featb[i] = *(const uint2*)tmp;
    } else if (b == 1616) {
        // Wp (L,3,256) + bp (L,256) -> Wpb[l][4][256] f16 (row 3 = bp)
        const int e8 = threadIdx.x * 8;
        const int l  = e8 >> 10;
        const int rr = (e8 >> 8) & 3;
        const int c  = e8 & 255;
        const float* src = (rr < 3) ? (Wp + (size_t)l * 768 + rr * 256 + c)
                                    : (bp + (size_t)l * 256 + c);
        const float4 f0 = ((const float4*)src)[0];
        const float4 f1 = ((const float4*)src)[1];
        _Float16 t[8] = {(_Float16)f0.x, (_Float16)f0.y, (_Float16)f0.z, (_Float16)f0.w,
                         (_Float16)f1.x, (_Float16)f1.y, (_Float16)f1.z, (_Float16)f1.w};
        *(uint4*)&Wpb[(size_t)l * 1024 + rr * 256 + c] = *(const uint4*)t;
    } else {
        // W_in fp32 [64][256] -> bf16 row-major copy (16 blocks x 1024 elems)
        const int i = (b - 1617) * 1024 + threadIdx.x * 4;
        const float4 v = *(const float4*)&W_in[i];
        __hip_bfloat16 tmp[4] = {__float2bfloat16(v.x), __float2bfloat16(v.y),
                                 __float2bfloat16(v.z), __float2bfloat16(v.w)};
        *(uint2*)&WinB[i] = *(const uint2*)tmp;
    }
}

// ---------------------------------------------------------------------------
// bc[cc] = b_in . Wqkv1[:,cc] + bqkv1[cc]   (3 blocks: q, k, v; coalesced)
// ---------------------------------------------------------------------------
__global__ __launch_bounds__(256) void qkv1_bias_kernel(
    const float* __restrict__ b_in,
    const float* __restrict__ Wq, const float* __restrict__ bq,
    const float* __restrict__ Wk, const float* __restrict__ bk,
    const float* __restrict__ Wv, const float* __restrict__ bv,
    float* __restrict__ bc)
{
    const int seg = blockIdx.x;
    const int c   = threadIdx.x;
    const float* W  = seg == 0 ? Wq : (seg == 1 ? Wk : Wv);
    const float* bb = seg == 0 ? bq : (seg == 1 ? bk : bv);
    float acc = 0.f;
    for (int k = 0; k < 256; ++k)
        acc += b_in[k] * W[(size_t)k * 256 + c];
    bc[seg * 256 + c] = acc + bb[c];
}

// ---------------------------------------------------------------------------
// KNN attention, f16 qkv, folded positional encoding, 2 pts / 256 threads.
// ---------------------------------------------------------------------------
__global__ __launch_bounds__(256) void knn_attn_kernel(
    const float* __restrict__ xyz,        // [BPTS,3]
    const int*   __restrict__ idx,        // [BPTS,KNN]
    const _Float16* __restrict__ qkv,     // [BPTS,768] = q|k|v
    const _Float16* __restrict__ Wpb,     // [4][256]  (Wp rows + bp)
    __hip_bfloat16* __restrict__ o)       // [BPTS,256]
{
    const int tid = threadIdx.x;
    const int pt  = tid >> 7;
    const int lt  = tid & 127;
    const int p0  = blockIdx.x * 2;
    const int p   = p0 + pt;
    const int h   = lt >> 4;
    const int k   = lt & 15;

    __shared__ float s_rel[2][KNN][3];
    __shared__ float s_wq[2][8][4];
    __shared__ float s_attn[2][8][KNN];
    __shared__ float s_arel[2][8][3];
    __shared__ __align__(16) _Float16 v_lds[2][KNN][256];  // 16 KB

    // --- QK loads (oldest in flight) ---
    const int jrow = ((p >> 13) << 13) + idx[p * KNN + k];
    const h8* qp = (const h8*)(qkv + (size_t)p * 768 + h * 32);
    const h8* kp = (const h8*)(qkv + (size_t)jrow * 768 + 256 + h * 32);
    const h8 q0 = qp[0], q1 = qp[1];
    const h8 k0 = kp[0], k1 = kp[1];

    // --- async V staging: 32 rows x 512B; wave covers 8 rows ---
    {
        const int w = tid >> 6, ln = tid & 63;
        #pragma unroll
        for (int c = 0; c < 4; ++c) {
            const int grE = w * 8 + c * 2;              // even row id 0..30
            const int gr  = grE + (ln >> 5);
            const int ptw = grE >> 4, kkE = grE & 15;
            const int pg  = p0 + (gr >> 4);
            const int jr  = ((pg >> 13) << 13) + idx[pg * KNN + (gr & 15)];
            gload16(qkv + (size_t)jr * 768 + 512 + (ln & 31) * 8,
                    (char*)&v_lds[ptw][kkE][0]);
        }
    }

    // --- side computations while loads fly ---
    if (tid < 32) {
        const int pp = tid >> 4, kk = tid & 15;
        const int pg = p0 + pp;
        const int jr = ((pg >> 13) << 13) + idx[pg * KNN + kk];
        s_rel[pp][kk][0] = xyz[pg * 3 + 0] - xyz[jr * 3 + 0];
        s_rel[pp][kk][1] = xyz[pg * 3 + 1] - xyz[jr * 3 + 1];
        s_rel[pp][kk][2] = xyz[pg * 3 + 2] - xyz[jr * 3 + 2];
    } else if (tid < 96) {
        const int t2 = tid - 32;
        const int pp = t2 >> 5, hh = (t2 >> 2) & 7, j = t2 & 3;
        const h8* qr = (const h8*)(qkv + (size_t)(p0 + pp) * 768 + hh * 32);
        const h8* wr = (const h8*)(Wpb + j * 256 + hh * 32);
        const h8 a0 = qr[0], a1 = qr[1], b0 = wr[0], b1 = wr[1];
        float acc = 0.f;
        #pragma unroll
        for (int i = 0; i < 4; ++i)
            acc = __builtin_amdgcn_fdot2(((const h2*)&a0)[i], ((const h2*)&b0)[i], acc, false);
        #pragma unroll
        for (int i = 0; i < 4; ++i)
            acc = __builtin_amdgcn_fdot2(((const h2*)&a1)[i], ((const h2*)&b1)[i], acc, false);
        s_wq[pp][hh][j] = acc;
    }

    // --- QK dot (fdot2) ---
    float dot = 0.f;
    #pragma unroll
    for (int i = 0; i < 4; ++i)
        dot = __builtin_amdgcn_fdot2(((const h2*)&q0)[i], ((const h2*)&k0)[i], dot, false);
    #pragma unroll
    for (int i = 0; i < 4; ++i)
        dot = __builtin_amdgcn_fdot2(((const h2*)&q1)[i], ((const h2*)&k1)[i], dot, false);
    __syncthreads();

    // --- logit + softmax + arel ---
    const float r0 = s_rel[pt][k][0], r1 = s_rel[pt][k][1], r2 = s_rel[pt][k][2];
    const float logit = (dot + r0 * s_wq[pt][h][0] + r1 * s_wq[pt][h][1]
                             + r2 * s_wq[pt][h][2] + s_wq[pt][h][3])
                        * 0.1767766952966369f;
    float mx = logit;
    #pragma unroll
    for (int off = 8; off >= 1; off >>= 1)
        mx = fmaxf(mx, __shfl_xor(mx, off, 16));
    const float e = __expf(logit - mx);
    float den = e;
    #pragma unroll
    for (int off = 8; off >= 1; off >>= 1)
        den += __shfl_xor(den, off, 16);
    const float attn = e / den;
    s_attn[pt][h][k] = attn;

    float a0 = attn * r0, a1 = attn * r1, a2 = attn * r2;
    #pragma unroll
    for (int off = 8; off >= 1; off >>= 1) {
        a0 += __shfl_xor(a0, off, 16);
        a1 += __shfl_xor(a1, off, 16);
        a2 += __shfl_xor(a2, off, 16);
    }
    if (k == 0) {
        s_arel[pt][h][0] = a0;
        s_arel[pt][h][1] = a1;
        s_arel[pt][h][2] = a2;
    }
    __syncthreads();   // drains async V stage too

    // --- PV: thread = (pt, channel pair); head of ch == h ---
    {
        const int ch = lt * 2;
        float ax = 0.f, ay = 0.f;
        #pragma unroll
        for (int kk = 0; kk < KNN; ++kk) {
            const float a = s_attn[pt][h][kk];
            const h2 vf = *(const h2*)&v_lds[pt][kk][ch];
            ax += a * (float)vf.x;
            ay += a * (float)vf.y;
        }
        const h2 w0 = *(const h2*)&Wpb[ch];
        const h2 w1 = *(const h2*)&Wpb[256 + ch];
        const h2 w2 = *(const h2*)&Wpb[512 + ch];
        const h2 w3 = *(const h2*)&Wpb[768 + ch];
        const float g0 = s_arel[pt][h][0], g1 = s_arel[pt][h][1], g2 = s_arel[pt][h][2];
        ax += g0 * (float)w0.x + g1 * (float)w1.x + g2 * (float)w2.x + (float)w3.x;
        ay += g0 * (float)w0.y + g1 * (float)w1.y + g2 * (float)w2.y + (float)w3.y;
        *(uint*)&o[(size_t)p * 256 + ch] = packbf2(ax, ay);
    }
}

// ---------------------------------------------------------------------------
extern "C" void kernel_launch(void* const* d_in, const int* in_sizes, int n_in,
                              void* d_out, int out_size, void* d_ws, size_t ws_size,
                              hipStream_t stream)
{
    const float* xyzs     = (const float*)d_in[0];
    const float* features = (const float*)d_in[1];
    const int*   k_graph  = (const int*)  d_in[2];
    const float* W_in     = (const float*)d_in[3];
    const float* b_in     = (const float*)d_in[4];
    const float* Wq       = (const float*)d_in[5];
    const float* bq       = (const float*)d_in[6];
    const float* Wk       = (const float*)d_in[7];
    const float* bk       = (const float*)d_in[8];
    const float* Wv       = (const float*)d_in[9];
    const float* bv       = (const float*)d_in[10];
    const float* Wp       = (const float*)d_in[11];
    const float* bp       = (const float*)d_in[12];
    const float* Wo       = (const float*)d_in[13];
    const float* bo       = (const float*)d_in[14];
    const float* W_out    = (const float*)d_in[15];
    const float* b_out    = (const float*)d_in[16];

    __hip_bfloat16* featb = (__hip_bfloat16*)d_ws;       // 16384*64
    __hip_bfloat16* f     = featb + 1048576;             // 16384*256
    _Float16*       qkv   = (_Float16*)(f + 4194304);    // 16384*768 (f16)
    __hip_bfloat16* ob    = (__hip_bfloat16*)(qkv + 12582912);  // 16384*256
    __hip_bfloat16* WtIn  = ob + 4194304;                // 256*64
    __hip_bfloat16* WtQKV = WtIn + 16384;                // 2*768*256
    __hip_bfloat16* WtO   = WtQKV + 393216;              // 2*256*256
    __hip_bfloat16* WtOut = WtO + 131072;                // 256*256
    _Float16*       Wpb   = (_Float16*)(WtOut + 65536);  // 2*1024
    __hip_bfloat16* WcT   = (__hip_bfloat16*)(Wpb + 2048);  // 768*64
    float*          bc    = (float*)(WcT + 49152);       // 768
    __hip_bfloat16* WinB  = (__hip_bfloat16*)(bc + 768); // 64*256

    prep_kernel<<<1633, 256, 0, stream>>>(W_in, Wq, Wk, Wv, Wo, W_out, features,
                                          Wp, bp, WtIn, WtQKV, WtO, WtOut,
                                          featb, Wpb, WinB);
    qkv1_bias_kernel<<<3, 256, 0, stream>>>(b_in, Wq, bq, Wk, bk, Wv, bv, bc);

    // fused layer-1 weight: WcT[768][64] = WtQKV_l0 @ WinB^T  (BN=64, no bias)
    gemm_mfma<256, false, 1, false, 64, false><<<dim3(1, 6), 256, 0, stream>>>(
        WtQKV, WinB, nullptr, nullptr, nullptr, nullptr, WcT, 768, 64);

    // f = features @ W_in + b_in   (layer-1 residual)
    gemm_mfma<64, false, 1, false><<<dim3(2, 128), 256, 0, stream>>>(
        featb, WtIn, b_in, b_in, b_in, nullptr, f, BPTS, 256);

    // layer-1 qkv: features @ (W_in.Wqkv1) + bc   (K=64)
    gemm_mfma<64, false, 2, false><<<dim3(6, 128), 256, 0, stream>>>(
        featb, WcT, bc, bc + 256, bc + 512, nullptr, qkv, BPTS, 768);

    for (int l = 0; l < 2; ++l) {
        if (l == 1) {
            gemm_mfma<256, false, 2, false><<<dim3(6, 128), 256, 0, stream>>>(
                f, WtQKV + 196608,
                bq + 256, bk + 256, bv + 256, nullptr, qkv, BPTS, 768);
        }

        knn_attn_kernel<<<dim3(BPTS / 2), 256, 0, stream>>>(
            xyzs, k_graph, qkv, Wpb + (size_t)l * 1024, ob);

        // f = ob @ Wo + bo + f
        gemm_mfma<256, true, 1, false><<<dim3(2, 128), 256, 0, stream>>>(
            ob, WtO + (size_t)l * 65536,
            bo + l * 256, bo + l * 256, bo + l * 256, f, f, BPTS, 256);
    }

    // out = leaky_relu(f @ W_out + b_out), fp32
    gemm_mfma<256, false, 0, true><<<dim3(2, 128), 256, 0, stream>>>(
        f, WtOut, b_out, b_out, b_out, nullptr, (float*)d_out, BPTS, 256);
}

// Round 7
// 133.950 us; speedup vs baseline: 1.1994x; 1.0407x over previous
//
#include <hip/hip_runtime.h>
#include <hip/hip_bf16.h>

typedef __attribute__((ext_vector_type(8))) short bf16x8;
typedef __attribute__((ext_vector_type(4))) float f32x4;
typedef __attribute__((ext_vector_type(2))) _Float16 h2;
typedef __attribute__((ext_vector_type(8))) _Float16 h8;
typedef unsigned int uint;

constexpr int NPTS = 8192;
constexpr int BPTS = 16384;     // B*N
constexpr int KNN  = 16;

// async global->LDS, 16B per lane; LDS dest is wave-uniform base + lane*16.
__device__ __forceinline__ void gload16(const void* g, void* l) {
    __builtin_amdgcn_global_load_lds(
        (const __attribute__((address_space(1))) unsigned int*)g,
        (__attribute__((address_space(3))) unsigned int*)l, 16, 0, 0);
}

__device__ __forceinline__ uint packbf2(float a, float b) {
    union { __hip_bfloat16 h; unsigned short u; } ua, ub;
    ua.h = __float2bfloat16(a); ub.h = __float2bfloat16(b);
    return (uint)ua.u | ((uint)ub.u << 16);
}

// ---------------------------------------------------------------------------
// bf16 MFMA GEMM: C[M,N] = A[M,KD] @ Bt[N,KD]^T + bias (+res)(+lrelu)
// 128x128 tile, BK=64, 4 waves, 16x16x32 MFMA, fp32 acc, XOR-swizzled LDS.
// 2-phase double-buffer: issue next chunk's global_load_lds BEFORE computing
// the current chunk; ONE barrier per chunk (loads fly under the 32 MFMAs).
// OUTT: 0 = f32, 1 = bf16, 2 = f16
// ---------------------------------------------------------------------------
template<int KD, bool RES, int OUTT, bool LRELU>
__global__ __launch_bounds__(256) void gemm_mfma(
    const __hip_bfloat16* __restrict__ A,   // [M, KD]
    const __hip_bfloat16* __restrict__ Bt,  // [N, KD]
    const float* __restrict__ b0, const float* __restrict__ b1,
    const float* __restrict__ b2,
    const __hip_bfloat16* __restrict__ res, // [M, N] or null
    void* __restrict__ Cout, int M, int N)
{
    constexpr int NT = KD / 64;

    __shared__ __align__(16) __hip_bfloat16 As[2][128 * 64];   // 2 x 16 KB
    __shared__ __align__(16) __hip_bfloat16 Bs[2][128 * 64];   // 2 x 16 KB

    const int tid  = threadIdx.x;
    const int lane = tid & 63;
    const int wid  = tid >> 6;
    const int wm   = (wid >> 1) * 64;
    const int wn   = (wid & 1) * 64;
    const int bm   = blockIdx.y * 128;
    const int bn   = blockIdx.x * 128;

    const int srow8 = lane >> 3;                  // row & 7
    const int sslot = (lane & 7) ^ srow8;         // inverse-swizzled k-slot
    const int r = lane & 15;
    const int g = lane >> 4;

    auto STAGE = [&](int buf, int k0) {
        #pragma unroll
        for (int p = 0; p < 4; ++p) {
            const int row = p * 32 + wid * 8 + srow8;
            gload16(&A[(size_t)(bm + row) * KD + k0 + sslot * 8],
                    (char*)As[buf] + (p * 32 + wid * 8) * 128);
            gload16(&Bt[(size_t)(bn + row) * KD + k0 + sslot * 8],
                    (char*)Bs[buf] + (p * 32 + wid * 8) * 128);
        }
    };

    f32x4 acc[4][4] = {};

    STAGE(0, 0);
    __syncthreads();

    #pragma unroll
    for (int t = 0; t < NT; ++t) {
        const int cur = t & 1;
        if (t + 1 < NT) STAGE(cur ^ 1, (t + 1) * 64);   // prefetch next chunk

        bf16x8 af[2][4], bfr[2][4];
        #pragma unroll
        for (int s = 0; s < 2; ++s) {
            const int physA = (s * 4 + g) ^ (r & 7);
            #pragma unroll
            for (int mi = 0; mi < 4; ++mi)
                af[s][mi] = *(const bf16x8*)((const char*)As[cur] + (wm + mi * 16 + r) * 128 + physA * 16);
            #pragma unroll
            for (int ni = 0; ni < 4; ++ni)
                bfr[s][ni] = *(const bf16x8*)((const char*)Bs[cur] + (wn + ni * 16 + r) * 128 + physA * 16);
        }
        #pragma unroll
        for (int s = 0; s < 2; ++s)
            #pragma unroll
            for (int mi = 0; mi < 4; ++mi)
                #pragma unroll
                for (int ni = 0; ni < 4; ++ni)
                    acc[mi][ni] = __builtin_amdgcn_mfma_f32_16x16x32_bf16(
                        af[s][mi], bfr[s][ni], acc[mi][ni], 0, 0, 0);

        if (t + 1 < NT) __syncthreads();   // drains prefetch (flew under MFMA)
    }

    // epilogue: C row = (lane>>4)*4 + reg, col = lane&15
    #pragma unroll
    for (int ni = 0; ni < 4; ++ni) {
        const int col = bn + wn + ni * 16 + r;
        const float* bsel = (col < 256) ? b0 : (col < 512 ? b1 : b2);
        const float bias = bsel[col & 255];
        #pragma unroll
        for (int mi = 0; mi < 4; ++mi) {
            #pragma unroll
            for (int q = 0; q < 4; ++q) {
                const int row = bm + wm + mi * 16 + g * 4 + q;
                float v = acc[mi][ni][q] + bias;
                if (RES)  v += __bfloat162float(res[(size_t)row * N + col]);
                if (LRELU) v = v > 0.f ? v : 0.01f * v;
                if (OUTT == 0)      ((float*)Cout)[(size_t)row * N + col] = v;
                else if (OUTT == 1) ((__hip_bfloat16*)Cout)[(size_t)row * N + col] = __float2bfloat16(v);
                else                ((_Float16*)Cout)[(size_t)row * N + col] = (_Float16)v;
            }
        }
    }
}

// ---------------------------------------------------------------------------
// prep: weights fp32[K][N] -> bf16[N][K]; features -> bf16; Wp/bp -> f16 rows.
// ---------------------------------------------------------------------------
__global__ __launch_bounds__(256) void prep_kernel(
    const float* __restrict__ W_in, const float* __restrict__ Wq,
    const float* __restrict__ Wk,  const float* __restrict__ Wv,
    const float* __restrict__ Wo,  const float* __restrict__ W_out,
    const float* __restrict__ features,
    const float* __restrict__ Wp,  const float* __restrict__ bp,
    __hip_bfloat16* __restrict__ WtIn,  __hip_bfloat16* __restrict__ WtQKV,
    __hip_bfloat16* __restrict__ WtO,   __hip_bfloat16* __restrict__ WtOut,
    __hip_bfloat16* __restrict__ featb, _Float16* __restrict__ Wpb)
{
    const int b = blockIdx.x;
    if (b < 592) {
        const float* srcs[10] = {W_in, Wq, Wk, Wv, Wq + 65536, Wk + 65536,
                                 Wv + 65536, Wo, Wo + 65536, W_out};
        __hip_bfloat16* dsts[10] = {
            WtIn, WtQKV, WtQKV + 65536, WtQKV + 131072,
            WtQKV + 196608, WtQKV + 262144, WtQKV + 327680,
            WtO, WtO + 65536, WtOut};
        const int Ks[10]    = {64,256,256,256,256,256,256,256,256,256};
        const int start[10] = {0,16,80,144,208,272,336,400,464,528};
        int j = 0;
        #pragma unroll
        for (int i = 1; i < 10; ++i) if (b >= start[i]) j = i;
        const int t  = b - start[j];
        const int Kd = Ks[j];
        const int ntk = Kd >> 5;
        const int tn = t / ntk;
        const int tk = t - tn * ntk;

        __shared__ float s[32][33];
        const int tx = threadIdx.x & 31, ty = threadIdx.x >> 5;
        const float* src = srcs[j];
        #pragma unroll
        for (int i = 0; i < 4; ++i)
            s[ty + i * 8][tx] = src[(size_t)(tk * 32 + ty + i * 8) * 256 + tn * 32 + tx];
        __syncthreads();
        __hip_bfloat16* dst = dsts[j];
        #pragma unroll
        for (int i = 0; i < 4; ++i)
            dst[(size_t)(tn * 32 + ty + i * 8) * Kd + tk * 32 + tx] =
                __float2bfloat16(s[tx][ty + i * 8]);
    } else if (b < 1616) {
        const int i = (b - 592) * 1024 + threadIdx.x * 4;
        const float4 v = *(const float4*)&features[i];
        __hip_bfloat16 tmp[4] = {__float2bfloat16(v.x), __float2bfloat16(v.y),
                                 __float2bfloat16(v.z), __float2bfloat16(v.w)};
        *(uint2*)&featb[i] = *(const uint2*)tmp;
    } else {
        // Wp (L,3,256) + bp (L,256) -> Wpb[l][4][256] f16 (row 3 = bp)
        const int e8 = threadIdx.x * 8;
        const int l  = e8 >> 10;
        const int rr = (e8 >> 8) & 3;
        const int c  = e8 & 255;
        const float* src = (rr < 3) ? (Wp + (size_t)l * 768 + rr * 256 + c)
                                    : (bp + (size_t)l * 256 + c);
        const float4 f0 = ((const float4*)src)[0];
        const float4 f1 = ((const float4*)src)[1];
        _Float16 t[8] = {(_Float16)f0.x, (_Float16)f0.y, (_Float16)f0.z, (_Float16)f0.w,
                         (_Float16)f1.x, (_Float16)f1.y, (_Float16)f1.z, (_Float16)f1.w};
        *(uint4*)&Wpb[(size_t)l * 1024 + rr * 256 + c] = *(const uint4*)t;
    }
}

// ---------------------------------------------------------------------------
// KNN attention, f16 qkv, folded positional encoding, 2 pts / 256 threads.
// ---------------------------------------------------------------------------
__global__ __launch_bounds__(256) void knn_attn_kernel(
    const float* __restrict__ xyz,        // [BPTS,3]
    const int*   __restrict__ idx,        // [BPTS,KNN]
    const _Float16* __restrict__ qkv,     // [BPTS,768] = q|k|v
    const _Float16* __restrict__ Wpb,     // [4][256]  (Wp rows + bp)
    __hip_bfloat16* __restrict__ o)       // [BPTS,256]
{
    const int tid = threadIdx.x;
    const int pt  = tid >> 7;
    const int lt  = tid & 127;
    const int p0  = blockIdx.x * 2;
    const int p   = p0 + pt;
    const int h   = lt >> 4;
    const int k   = lt & 15;

    __shared__ float s_rel[2][KNN][3];
    __shared__ float s_wq[2][8][4];
    __shared__ float s_attn[2][8][KNN];
    __shared__ float s_arel[2][8][3];
    __shared__ __align__(16) _Float16 v_lds[2][KNN][256];  // 16 KB

    // --- QK loads (oldest in flight) ---
    const int jrow = ((p >> 13) << 13) + idx[p * KNN + k];
    const h8* qp = (const h8*)(qkv + (size_t)p * 768 + h * 32);
    const h8* kp = (const h8*)(qkv + (size_t)jrow * 768 + 256 + h * 32);
    const h8 q0 = qp[0], q1 = qp[1];
    const h8 k0 = kp[0], k1 = kp[1];

    // --- async V staging: 32 rows x 512B; wave covers 8 rows ---
    {
        const int w = tid >> 6, ln = tid & 63;
        #pragma unroll
        for (int c = 0; c < 4; ++c) {
            const int grE = w * 8 + c * 2;              // even row id 0..30
            const int gr  = grE + (ln >> 5);
            const int ptw = grE >> 4, kkE = grE & 15;
            const int pg  = p0 + (gr >> 4);
            const int jr  = ((pg >> 13) << 13) + idx[pg * KNN + (gr & 15)];
            gload16(qkv + (size_t)jr * 768 + 512 + (ln & 31) * 8,
                    (char*)&v_lds[ptw][kkE][0]);
        }
    }

    // --- side computations while loads fly ---
    if (tid < 32) {
        const int pp = tid >> 4, kk = tid & 15;
        const int pg = p0 + pp;
        const int jr = ((pg >> 13) << 13) + idx[pg * KNN + kk];
        s_rel[pp][kk][0] = xyz[pg * 3 + 0] - xyz[jr * 3 + 0];
        s_rel[pp][kk][1] = xyz[pg * 3 + 1] - xyz[jr * 3 + 1];
        s_rel[pp][kk][2] = xyz[pg * 3 + 2] - xyz[jr * 3 + 2];
    } else if (tid < 96) {
        const int t2 = tid - 32;
        const int pp = t2 >> 5, hh = (t2 >> 2) & 7, j = t2 & 3;
        const h8* qr = (const h8*)(qkv + (size_t)(p0 + pp) * 768 + hh * 32);
        const h8* wr = (const h8*)(Wpb + j * 256 + hh * 32);
        const h8 a0 = qr[0], a1 = qr[1], b0 = wr[0], b1 = wr[1];
        float acc = 0.f;
        #pragma unroll
        for (int i = 0; i < 4; ++i)
            acc = __builtin_amdgcn_fdot2(((const h2*)&a0)[i], ((const h2*)&b0)[i], acc, false);
        #pragma unroll
        for (int i = 0; i < 4; ++i)
            acc = __builtin_amdgcn_fdot2(((const h2*)&a1)[i], ((const h2*)&b1)[i], acc, false);
        s_wq[pp][hh][j] = acc;
    }

    // --- QK dot (fdot2) ---
    float dot = 0.f;
    #pragma unroll
    for (int i = 0; i < 4; ++i)
        dot = __builtin_amdgcn_fdot2(((const h2*)&q0)[i], ((const h2*)&k0)[i], dot, false);
    #pragma unroll
    for (int i = 0; i < 4; ++i)
        dot = __builtin_amdgcn_fdot2(((const h2*)&q1)[i], ((const h2*)&k1)[i], dot, false);
    __syncthreads();

    // --- logit + softmax + arel ---
    const float r0 = s_rel[pt][k][0], r1 = s_rel[pt][k][1], r2 = s_rel[pt][k][2];
    const float logit = (dot + r0 * s_wq[pt][h][0] + r1 * s_wq[pt][h][1]
                             + r2 * s_wq[pt][h][2] + s_wq[pt][h][3])
                        * 0.1767766952966369f;
    float mx = logit;
    #pragma unroll
    for (int off = 8; off >= 1; off >>= 1)
        mx = fmaxf(mx, __shfl_xor(mx, off, 16));
    const float e = __expf(logit - mx);
    float den = e;
    #pragma unroll
    for (int off = 8; off >= 1; off >>= 1)
        den += __shfl_xor(den, off, 16);
    const float attn = e / den;
    s_attn[pt][h][k] = attn;

    float a0 = attn * r0, a1 = attn * r1, a2 = attn * r2;
    #pragma unroll
    for (int off = 8; off >= 1; off >>= 1) {
        a0 += __shfl_xor(a0, off, 16);
        a1 += __shfl_xor(a1, off, 16);
        a2 += __shfl_xor(a2, off, 16);
    }
    if (k == 0) {
        s_arel[pt][h][0] = a0;
        s_arel[pt][h][1] = a1;
        s_arel[pt][h][2] = a2;
    }
    __syncthreads();   // drains async V stage too

    // --- PV: thread = (pt, channel pair); head of ch == h ---
    {
        const int ch = lt * 2;
        float ax = 0.f, ay = 0.f;
        #pragma unroll
        for (int kk = 0; kk < KNN; ++kk) {
            const float a = s_attn[pt][h][kk];
            const h2 vf = *(const h2*)&v_lds[pt][kk][ch];
            ax += a * (float)vf.x;
            ay += a * (float)vf.y;
        }
        const h2 w0 = *(const h2*)&Wpb[ch];
        const h2 w1 = *(const h2*)&Wpb[256 + ch];
        const h2 w2 = *(const h2*)&Wpb[512 + ch];
        const h2 w3 = *(const h2*)&Wpb[768 + ch];
        const float g0 = s_arel[pt][h][0], g1 = s_arel[pt][h][1], g2 = s_arel[pt][h][2];
        ax += g0 * (float)w0.x + g1 * (float)w1.x + g2 * (float)w2.x + (float)w3.x;
        ay += g0 * (float)w0.y + g1 * (float)w1.y + g2 * (float)w2.y + (float)w3.y;
        *(uint*)&o[(size_t)p * 256 + ch] = packbf2(ax, ay);
    }
}

// ---------------------------------------------------------------------------
extern "C" void kernel_launch(void* const* d_in, const int* in_sizes, int n_in,
                              void* d_out, int out_size, void* d_ws, size_t ws_size,
                              hipStream_t stream)
{
    const float* xyzs     = (const float*)d_in[0];
    const float* features = (const float*)d_in[1];
    const int*   k_graph  = (const int*)  d_in[2];
    const float* W_in     = (const float*)d_in[3];
    const float* b_in     = (const float*)d_in[4];
    const float* Wq       = (const float*)d_in[5];
    const float* bq       = (const float*)d_in[6];
    const float* Wk       = (const float*)d_in[7];
    const float* bk       = (const float*)d_in[8];
    const float* Wv       = (const float*)d_in[9];
    const float* bv       = (const float*)d_in[10];
    const float* Wp       = (const float*)d_in[11];
    const float* bp       = (const float*)d_in[12];
    const float* Wo       = (const float*)d_in[13];
    const float* bo       = (const float*)d_in[14];
    const float* W_out    = (const float*)d_in[15];
    const float* b_out    = (const float*)d_in[16];

    __hip_bfloat16* featb = (__hip_bfloat16*)d_ws;       // 16384*64
    __hip_bfloat16* f     = featb + 1048576;             // 16384*256
    _Float16*       qkv   = (_Float16*)(f + 4194304);    // 16384*768 (f16)
    __hip_bfloat16* ob    = (__hip_bfloat16*)(qkv + 12582912);  // 16384*256
    __hip_bfloat16* WtIn  = ob + 4194304;                // 256*64
    __hip_bfloat16* WtQKV = WtIn + 16384;                // 2*768*256
    __hip_bfloat16* WtO   = WtQKV + 393216;              // 2*256*256
    __hip_bfloat16* WtOut = WtO + 131072;                // 256*256
    _Float16*       Wpb   = (_Float16*)(WtOut + 65536);  // 2*1024

    prep_kernel<<<1617, 256, 0, stream>>>(W_in, Wq, Wk, Wv, Wo, W_out, features,
                                          Wp, bp, WtIn, WtQKV, WtO, WtOut,
                                          featb, Wpb);

    // f = features @ W_in + b_in
    gemm_mfma<64, false, 1, false><<<dim3(2, 128), 256, 0, stream>>>(
        featb, WtIn, b_in, b_in, b_in, nullptr, f, BPTS, 256);

    for (int l = 0; l < 2; ++l) {
        gemm_mfma<256, false, 2, false><<<dim3(6, 128), 256, 0, stream>>>(
            f, WtQKV + (size_t)l * 196608,
            bq + l * 256, bk + l * 256, bv + l * 256, nullptr, qkv, BPTS, 768);

        knn_attn_kernel<<<dim3(BPTS / 2), 256, 0, stream>>>(
            xyzs, k_graph, qkv, Wpb + (size_t)l * 1024, ob);

        // f = ob @ Wo + bo + f
        gemm_mfma<256, true, 1, false><<<dim3(2, 128), 256, 0, stream>>>(
            ob, WtO + (size_t)l * 65536,
            bo + l * 256, bo + l * 256, bo + l * 256, f, f, BPTS, 256);
    }

    // out = leaky_relu(f @ W_out + b_out), fp32
    gemm_mfma<256, false, 0, true><<<dim3(2, 128), 256, 0, stream>>>(
        f, WtOut, b_out, b_out, b_out, nullptr, (float*)d_out, BPTS, 256);
}

// Round 8
// 133.321 us; speedup vs baseline: 1.2050x; 1.0047x over previous
//
#include <hip/hip_runtime.h>
#include <hip/hip_bf16.h>

typedef __attribute__((ext_vector_type(8))) short bf16x8;
typedef __attribute__((ext_vector_type(4))) float f32x4;
typedef __attribute__((ext_vector_type(2))) _Float16 h2;
typedef __attribute__((ext_vector_type(8))) _Float16 h8;
typedef unsigned int uint;

constexpr int NPTS = 8192;
constexpr int BPTS = 16384;     // B*N
constexpr int KNN  = 16;

// async global->LDS, 16B per lane; LDS dest is wave-uniform base + lane*16.
__device__ __forceinline__ void gload16(const void* g, void* l) {
    __builtin_amdgcn_global_load_lds(
        (const __attribute__((address_space(1))) unsigned int*)g,
        (__attribute__((address_space(3))) unsigned int*)l, 16, 0, 0);
}

// ---------------------------------------------------------------------------
// bf16 MFMA GEMM (round-4 version, best measured): C = A @ Bt^T + bias
// 128x128 tile, BK=64, 4 waves, 16x16x32 MFMA, fp32 acc, XOR-swizzled LDS.
// OUTT: 0 = f32, 1 = bf16, 2 = f16
// ---------------------------------------------------------------------------
template<int KD, bool RES, int OUTT, bool LRELU>
__global__ __launch_bounds__(256) void gemm_mfma(
    const __hip_bfloat16* __restrict__ A,   // [M, KD]
    const __hip_bfloat16* __restrict__ Bt,  // [N, KD]
    const float* __restrict__ b0, const float* __restrict__ b1,
    const float* __restrict__ b2,
    const __hip_bfloat16* __restrict__ res, // [M, N] or null
    void* __restrict__ Cout, int M, int N)
{
    __shared__ __align__(16) __hip_bfloat16 As[128 * 64];
    __shared__ __align__(16) __hip_bfloat16 Bs[128 * 64];

    const int tid  = threadIdx.x;
    const int lane = tid & 63;
    const int wid  = tid >> 6;
    const int wm   = (wid >> 1) * 64;
    const int wn   = (wid & 1) * 64;
    const int bm   = blockIdx.y * 128;
    const int bn   = blockIdx.x * 128;

    const int srow8 = lane >> 3;
    const int sslot = (lane & 7) ^ srow8;
    const int r = lane & 15;
    const int g = lane >> 4;

    f32x4 acc[4][4] = {};

    for (int k0 = 0; k0 < KD; k0 += 64) {
        #pragma unroll
        for (int p = 0; p < 4; ++p) {
            const int rowA = p * 32 + wid * 8 + srow8;
            gload16(&A[(size_t)(bm + rowA) * KD + k0 + sslot * 8],
                    (char*)As + (p * 32 + wid * 8) * 128);
            gload16(&Bt[(size_t)(bn + rowA) * KD + k0 + sslot * 8],
                    (char*)Bs + (p * 32 + wid * 8) * 128);
        }
        __syncthreads();

        bf16x8 af[2][4], bfr[2][4];
        #pragma unroll
        for (int s = 0; s < 2; ++s) {
            const int physA = (s * 4 + g) ^ (r & 7);
            #pragma unroll
            for (int mi = 0; mi < 4; ++mi)
                af[s][mi] = *(const bf16x8*)((const char*)As + (wm + mi * 16 + r) * 128 + physA * 16);
            #pragma unroll
            for (int ni = 0; ni < 4; ++ni)
                bfr[s][ni] = *(const bf16x8*)((const char*)Bs + (wn + ni * 16 + r) * 128 + physA * 16);
        }
        #pragma unroll
        for (int s = 0; s < 2; ++s)
            #pragma unroll
            for (int mi = 0; mi < 4; ++mi)
                #pragma unroll
                for (int ni = 0; ni < 4; ++ni)
                    acc[mi][ni] = __builtin_amdgcn_mfma_f32_16x16x32_bf16(
                        af[s][mi], bfr[s][ni], acc[mi][ni], 0, 0, 0);
        __syncthreads();
    }

    #pragma unroll
    for (int ni = 0; ni < 4; ++ni) {
        const int col = bn + wn + ni * 16 + r;
        const float* bsel = (col < 256) ? b0 : (col < 512 ? b1 : b2);
        const float bias = bsel[col & 255];
        #pragma unroll
        for (int mi = 0; mi < 4; ++mi) {
            #pragma unroll
            for (int q = 0; q < 4; ++q) {
                const int row = bm + wm + mi * 16 + g * 4 + q;
                float v = acc[mi][ni][q] + bias;
                if (RES)  v += __bfloat162float(res[(size_t)row * N + col]);
                if (LRELU) v = v > 0.f ? v : 0.01f * v;
                if (OUTT == 0)      ((float*)Cout)[(size_t)row * N + col] = v;
                else if (OUTT == 1) ((__hip_bfloat16*)Cout)[(size_t)row * N + col] = __float2bfloat16(v);
                else                ((_Float16*)Cout)[(size_t)row * N + col] = (_Float16)v;
            }
        }
    }
}

// ---------------------------------------------------------------------------
// prep: weights fp32[K][N] -> bf16[N][K]; features -> bf16; Wp/bp -> f16 rows.
// ---------------------------------------------------------------------------
__global__ __launch_bounds__(256) void prep_kernel(
    const float* __restrict__ W_in, const float* __restrict__ Wq,
    const float* __restrict__ Wk,  const float* __restrict__ Wv,
    const float* __restrict__ Wo,  const float* __restrict__ W_out,
    const float* __restrict__ features,
    const float* __restrict__ Wp,  const float* __restrict__ bp,
    __hip_bfloat16* __restrict__ WtIn,  __hip_bfloat16* __restrict__ WtQKV,
    __hip_bfloat16* __restrict__ WtO,   __hip_bfloat16* __restrict__ WtOut,
    __hip_bfloat16* __restrict__ featb, _Float16* __restrict__ Wpb)
{
    const int b = blockIdx.x;
    if (b < 592) {
        const float* srcs[10] = {W_in, Wq, Wk, Wv, Wq + 65536, Wk + 65536,
                                 Wv + 65536, Wo, Wo + 65536, W_out};
        __hip_bfloat16* dsts[10] = {
            WtIn, WtQKV, WtQKV + 65536, WtQKV + 131072,
            WtQKV + 196608, WtQKV + 262144, WtQKV + 327680,
            WtO, WtO + 65536, WtOut};
        const int Ks[10]    = {64,256,256,256,256,256,256,256,256,256};
        const int start[10] = {0,16,80,144,208,272,336,400,464,528};
        int j = 0;
        #pragma unroll
        for (int i = 1; i < 10; ++i) if (b >= start[i]) j = i;
        const int t  = b - start[j];
        const int Kd = Ks[j];
        const int ntk = Kd >> 5;
        const int tn = t / ntk;
        const int tk = t - tn * ntk;

        __shared__ float s[32][33];
        const int tx = threadIdx.x & 31, ty = threadIdx.x >> 5;
        const float* src = srcs[j];
        #pragma unroll
        for (int i = 0; i < 4; ++i)
            s[ty + i * 8][tx] = src[(size_t)(tk * 32 + ty + i * 8) * 256 + tn * 32 + tx];
        __syncthreads();
        __hip_bfloat16* dst = dsts[j];
        #pragma unroll
        for (int i = 0; i < 4; ++i)
            dst[(size_t)(tn * 32 + ty + i * 8) * Kd + tk * 32 + tx] =
                __float2bfloat16(s[tx][ty + i * 8]);
    } else if (b < 1616) {
        const int i = (b - 592) * 1024 + threadIdx.x * 4;
        const float4 v = *(const float4*)&features[i];
        __hip_bfloat16 tmp[4] = {__float2bfloat16(v.x), __float2bfloat16(v.y),
                                 __float2bfloat16(v.z), __float2bfloat16(v.w)};
        *(uint2*)&featb[i] = *(const uint2*)tmp;
    } else {
        // Wp (L,3,256) + bp (L,256) -> Wpb[l][4][256] f16 (row 3 = bp)
        const int e8 = threadIdx.x * 8;
        const int l  = e8 >> 10;
        const int rr = (e8 >> 8) & 3;
        const int c  = e8 & 255;
        const float* src = (rr < 3) ? (Wp + (size_t)l * 768 + rr * 256 + c)
                                    : (bp + (size_t)l * 256 + c);
        const float4 f0 = ((const float4*)src)[0];
        const float4 f1 = ((const float4*)src)[1];
        _Float16 t[8] = {(_Float16)f0.x, (_Float16)f0.y, (_Float16)f0.z, (_Float16)f0.w,
                         (_Float16)f1.x, (_Float16)f1.y, (_Float16)f1.z, (_Float16)f1.w};
        *(uint4*)&Wpb[(size_t)l * 1024 + rr * 256 + c] = *(const uint4*)t;
    }
}

// ---------------------------------------------------------------------------
// KNN attention, f16 qkv, folded pos-encoding, tr-read PV.
// 2 pts / 256 threads.  V staged reg->LDS in [kt][ct][4][16] f16 subtiles;
// PV uses ds_read_b64_tr_b16 (lane gets 4 k-adjacent vals for one ch) and
// fdot2 with f16-packed attn weights (f32 accumulate).
// ---------------------------------------------------------------------------
__global__ __launch_bounds__(256) void knn_attn_kernel(
    const float* __restrict__ xyz,        // [BPTS,3]
    const int*   __restrict__ idx,        // [BPTS,KNN]
    const _Float16* __restrict__ qkv,     // [BPTS,768] = q|k|v
    const _Float16* __restrict__ Wpb,     // [4][256]  (Wp rows + bp)
    __hip_bfloat16* __restrict__ o)       // [BPTS,256]
{
    const int tid = threadIdx.x;
    const int pt  = tid >> 7;
    const int lt  = tid & 127;
    const int p0  = blockIdx.x * 2;
    const int p   = p0 + pt;
    const int hh  = lt >> 4;
    const int k   = lt & 15;

    __shared__ float s_rel[2][KNN][3];
    __shared__ float s_wq[2][8][4];
    __shared__ _Float16 s_ah[2][8][KNN];                 // attn weights, f16
    __shared__ float s_arel[2][8][3];
    __shared__ __align__(16) char v_raw[16384];          // V subtiled, 2x8KB

    // --- QK loads (oldest in flight) ---
    const int jrow = ((p >> 13) << 13) + idx[p * KNN + k];
    const h8* qp = (const h8*)(qkv + (size_t)p * 768 + hh * 32);
    const h8* kp = (const h8*)(qkv + (size_t)jrow * 768 + 256 + hh * 32);
    const h8 q0 = qp[0], q1 = qp[1];
    const h8 k0 = kp[0], k1 = kp[1];

    // --- V reg staging: thread owns row sk, 4x16B chunks (ch = 8*c4 + 64i) ---
    const int sk = lt >> 3;                  // 0..15 neighbor row
    const int c4 = lt & 7;
    const int jr_st = ((p >> 13) << 13) + idx[p * KNN + sk];
    const uint4* vsrc = (const uint4*)(qkv + (size_t)jr_st * 768 + 512 + c4 * 8);
    const uint4 st0 = vsrc[0];
    const uint4 st1 = vsrc[8];
    const uint4 st2 = vsrc[16];
    const uint4 st3 = vsrc[24];
    // LDS dest: pt*8192 + (sk>>2)*2048 + ct*128 + (sk&3)*32 + half*16,
    // ct = c>>1, half = c&1, c = c4 + 8i  ->  base + 512*i
    const int dbase = pt * 8192 + (sk >> 2) * 2048 + (c4 >> 1) * 128
                    + (sk & 3) * 32 + (c4 & 1) * 16;

    // --- side computations while loads fly ---
    if (tid < 32) {
        const int pp = tid >> 4, kk = tid & 15;
        const int pg = p0 + pp;
        const int jr = ((pg >> 13) << 13) + idx[pg * KNN + kk];
        s_rel[pp][kk][0] = xyz[pg * 3 + 0] - xyz[jr * 3 + 0];
        s_rel[pp][kk][1] = xyz[pg * 3 + 1] - xyz[jr * 3 + 1];
        s_rel[pp][kk][2] = xyz[pg * 3 + 2] - xyz[jr * 3 + 2];
    } else if (tid < 96) {
        const int t2 = tid - 32;
        const int pp = t2 >> 5, hq = (t2 >> 2) & 7, j = t2 & 3;
        const h8* qr = (const h8*)(qkv + (size_t)(p0 + pp) * 768 + hq * 32);
        const h8* wr = (const h8*)(Wpb + j * 256 + hq * 32);
        const h8 a0 = qr[0], a1 = qr[1], b0 = wr[0], b1 = wr[1];
        float acc = 0.f;
        #pragma unroll
        for (int i = 0; i < 4; ++i)
            acc = __builtin_amdgcn_fdot2(((const h2*)&a0)[i], ((const h2*)&b0)[i], acc, false);
        #pragma unroll
        for (int i = 0; i < 4; ++i)
            acc = __builtin_amdgcn_fdot2(((const h2*)&a1)[i], ((const h2*)&b1)[i], acc, false);
        s_wq[pp][hq][j] = acc;
    }

    // --- QK dot (fdot2) ---
    float dot = 0.f;
    #pragma unroll
    for (int i = 0; i < 4; ++i)
        dot = __builtin_amdgcn_fdot2(((const h2*)&q0)[i], ((const h2*)&k0)[i], dot, false);
    #pragma unroll
    for (int i = 0; i < 4; ++i)
        dot = __builtin_amdgcn_fdot2(((const h2*)&q1)[i], ((const h2*)&k1)[i], dot, false);
    __syncthreads();

    // --- logit + softmax + arel ---
    const float r0 = s_rel[pt][k][0], r1 = s_rel[pt][k][1], r2 = s_rel[pt][k][2];
    const float logit = (dot + r0 * s_wq[pt][hh][0] + r1 * s_wq[pt][hh][1]
                             + r2 * s_wq[pt][hh][2] + s_wq[pt][hh][3])
                        * 0.1767766952966369f;
    float mx = logit;
    #pragma unroll
    for (int off = 8; off >= 1; off >>= 1)
        mx = fmaxf(mx, __shfl_xor(mx, off, 16));
    const float e = __expf(logit - mx);
    float den = e;
    #pragma unroll
    for (int off = 8; off >= 1; off >>= 1)
        den += __shfl_xor(den, off, 16);
    const float attn = e / den;
    s_ah[pt][hh][k] = (_Float16)attn;

    float a0 = attn * r0, a1 = attn * r1, a2 = attn * r2;
    #pragma unroll
    for (int off = 8; off >= 1; off >>= 1) {
        a0 += __shfl_xor(a0, off, 16);
        a1 += __shfl_xor(a1, off, 16);
        a2 += __shfl_xor(a2, off, 16);
    }
    if (k == 0) {
        s_arel[pt][hh][0] = a0;
        s_arel[pt][hh][1] = a1;
        s_arel[pt][hh][2] = a2;
    }

    // --- V staging LDS writes (loads have had QK+softmax to land) ---
    *(uint4*)(v_raw + dbase +    0) = st0;
    *(uint4*)(v_raw + dbase +  512) = st1;
    *(uint4*)(v_raw + dbase + 1024) = st2;
    *(uint4*)(v_raw + dbase + 1536) = st3;
    __syncthreads();

    // --- PV via hardware transpose reads ---
    {
        const int w   = tid >> 6;          // wave 0..3
        const int l   = tid & 63;
        const int pt2 = w >> 1;
        const int H   = w & 1;             // ch half (128)
        const int g   = l >> 4;
        const int li  = l & 15;
        const int chA = H * 128 + g * 16 + li;
        const int chB = chA + 64;
        const int hA  = chA >> 5, hB = chB >> 5;
        const int p2  = p0 + pt2;

        const unsigned vg = (unsigned)(size_t)
            (__attribute__((address_space(3))) char*)(v_raw + pt2 * 8192 + H * 1024 + l * 8);

        uint2 rA0, rA1, rA2, rA3, rB0, rB1, rB2, rB3;
        asm volatile("ds_read_b64_tr_b16 %0, %1 offset:0"    : "=v"(rA0) : "v"(vg));
        asm volatile("ds_read_b64_tr_b16 %0, %1 offset:2048" : "=v"(rA1) : "v"(vg));
        asm volatile("ds_read_b64_tr_b16 %0, %1 offset:4096" : "=v"(rA2) : "v"(vg));
        asm volatile("ds_read_b64_tr_b16 %0, %1 offset:6144" : "=v"(rA3) : "v"(vg));
        asm volatile("ds_read_b64_tr_b16 %0, %1 offset:512"  : "=v"(rB0) : "v"(vg));
        asm volatile("ds_read_b64_tr_b16 %0, %1 offset:2560" : "=v"(rB1) : "v"(vg));
        asm volatile("ds_read_b64_tr_b16 %0, %1 offset:4608" : "=v"(rB2) : "v"(vg));
        asm volatile("ds_read_b64_tr_b16 %0, %1 offset:6656" : "=v"(rB3) : "v"(vg));
        asm volatile("s_waitcnt lgkmcnt(0)" ::: "memory");
        __builtin_amdgcn_sched_barrier(0);

        const h2* aA = (const h2*)&s_ah[pt2][hA][0];   // 8 h2 = k pairs
        const h2* aB = (const h2*)&s_ah[pt2][hB][0];

        float oA = 0.f, oB = 0.f;
        #define PVKT(rr, aa, acc, kt)                                             \
            acc = __builtin_amdgcn_fdot2(aa[2*kt],   *(const h2*)&rr.x, acc, false); \
            acc = __builtin_amdgcn_fdot2(aa[2*kt+1], *(const h2*)&rr.y, acc, false);
        PVKT(rA0, aA, oA, 0) PVKT(rA1, aA, oA, 1) PVKT(rA2, aA, oA, 2) PVKT(rA3, aA, oA, 3)
        PVKT(rB0, aB, oB, 0) PVKT(rB1, aB, oB, 1) PVKT(rB2, aB, oB, 2) PVKT(rB3, aB, oB, 3)
        #undef PVKT

        const float gA0 = s_arel[pt2][hA][0], gA1 = s_arel[pt2][hA][1], gA2 = s_arel[pt2][hA][2];
        const float gB0 = s_arel[pt2][hB][0], gB1 = s_arel[pt2][hB][1], gB2 = s_arel[pt2][hB][2];
        oA += gA0 * (float)Wpb[chA] + gA1 * (float)Wpb[256 + chA]
            + gA2 * (float)Wpb[512 + chA] + (float)Wpb[768 + chA];
        oB += gB0 * (float)Wpb[chB] + gB1 * (float)Wpb[256 + chB]
            + gB2 * (float)Wpb[512 + chB] + (float)Wpb[768 + chB];
        o[(size_t)p2 * 256 + chA] = __float2bfloat16(oA);
        o[(size_t)p2 * 256 + chB] = __float2bfloat16(oB);
    }
}

// ---------------------------------------------------------------------------
extern "C" void kernel_launch(void* const* d_in, const int* in_sizes, int n_in,
                              void* d_out, int out_size, void* d_ws, size_t ws_size,
                              hipStream_t stream)
{
    const float* xyzs     = (const float*)d_in[0];
    const float* features = (const float*)d_in[1];
    const int*   k_graph  = (const int*)  d_in[2];
    const float* W_in     = (const float*)d_in[3];
    const float* b_in     = (const float*)d_in[4];
    const float* Wq       = (const float*)d_in[5];
    const float* bq       = (const float*)d_in[6];
    const float* Wk       = (const float*)d_in[7];
    const float* bk       = (const float*)d_in[8];
    const float* Wv       = (const float*)d_in[9];
    const float* bv       = (const float*)d_in[10];
    const float* Wp       = (const float*)d_in[11];
    const float* bp       = (const float*)d_in[12];
    const float* Wo       = (const float*)d_in[13];
    const float* bo       = (const float*)d_in[14];
    const float* W_out    = (const float*)d_in[15];
    const float* b_out    = (const float*)d_in[16];

    __hip_bfloat16* featb = (__hip_bfloat16*)d_ws;       // 16384*64
    __hip_bfloat16* f     = featb + 1048576;             // 16384*256
    _Float16*       qkv   = (_Float16*)(f + 4194304);    // 16384*768 (f16)
    __hip_bfloat16* ob    = (__hip_bfloat16*)(qkv + 12582912);  // 16384*256
    __hip_bfloat16* WtIn  = ob + 4194304;                // 256*64
    __hip_bfloat16* WtQKV = WtIn + 16384;                // 2*768*256
    __hip_bfloat16* WtO   = WtQKV + 393216;              // 2*256*256
    __hip_bfloat16* WtOut = WtO + 131072;                // 256*256
    _Float16*       Wpb   = (_Float16*)(WtOut + 65536);  // 2*1024

    prep_kernel<<<1617, 256, 0, stream>>>(W_in, Wq, Wk, Wv, Wo, W_out, features,
                                          Wp, bp, WtIn, WtQKV, WtO, WtOut,
                                          featb, Wpb);

    // f = features @ W_in + b_in
    gemm_mfma<64, false, 1, false><<<dim3(2, 128), 256, 0, stream>>>(
        featb, WtIn, b_in, b_in, b_in, nullptr, f, BPTS, 256);

    for (int l = 0; l < 2; ++l) {
        gemm_mfma<256, false, 2, false><<<dim3(6, 128), 256, 0, stream>>>(
            f, WtQKV + (size_t)l * 196608,
            bq + l * 256, bk + l * 256, bv + l * 256, nullptr, qkv, BPTS, 768);

        knn_attn_kernel<<<dim3(BPTS / 2), 256, 0, stream>>>(
            xyzs, k_graph, qkv, Wpb + (size_t)l * 1024, ob);

        // f = ob @ Wo + bo + f
        gemm_mfma<256, true, 1, false><<<dim3(2, 128), 256, 0, stream>>>(
            ob, WtO + (size_t)l * 65536,
            bo + l * 256, bo + l * 256, bo + l * 256, f, f, BPTS, 256);
    }

    // out = leaky_relu(f @ W_out + b_out), fp32
    gemm_mfma<256, false, 0, true><<<dim3(2, 128), 256, 0, stream>>>(
        f, WtOut, b_out, b_out, b_out, nullptr, (float*)d_out, BPTS, 256);
}

// Round 9
// 127.870 us; speedup vs baseline: 1.2564x; 1.0426x over previous
//
#include <hip/hip_runtime.h>
#include <hip/hip_bf16.h>

typedef __attribute__((ext_vector_type(8))) short bf16x8;
typedef __attribute__((ext_vector_type(4))) float f32x4;
typedef __attribute__((ext_vector_type(2))) _Float16 h2;
typedef __attribute__((ext_vector_type(8))) _Float16 h8;
typedef unsigned int uint;

constexpr int NPTS = 8192;
constexpr int BPTS = 16384;     // B*N
constexpr int KNN  = 16;

// async global->LDS, 16B per lane; LDS dest is wave-uniform base + lane*16.
__device__ __forceinline__ void gload16(const void* g, void* l) {
    __builtin_amdgcn_global_load_lds(
        (const __attribute__((address_space(1))) unsigned int*)g,
        (__attribute__((address_space(3))) unsigned int*)l, 16, 0, 0);
}

// ---------------------------------------------------------------------------
// bf16 MFMA GEMM: C[M,N] = A[M,KD] @ Bt[N,KD]^T + bias (+res)(+lrelu)
// BM template (128 for N=768 qkv GEMMs; 64 for N=256 GEMMs -> 2x grid,
// 2-4 blocks/CU instead of 1). BN=128, BK=64, 4 waves, 16x16x32 MFMA,
// fp32 acc, XOR-swizzled LDS staged via global_load_lds.
// OUTT: 0 = f32, 1 = bf16, 2 = f16
// ---------------------------------------------------------------------------
template<int KD, bool RES, int OUTT, bool LRELU, int BM = 128>
__global__ __launch_bounds__(256) void gemm_mfma(
    const __hip_bfloat16* __restrict__ A,   // [M, KD]
    const __hip_bfloat16* __restrict__ Bt,  // [N, KD]
    const float* __restrict__ b0, const float* __restrict__ b1,
    const float* __restrict__ b2,
    const __hip_bfloat16* __restrict__ res, // [M, N] or null
    void* __restrict__ Cout, int M, int N)
{
    constexpr int WM = BM / 2;        // per-wave M extent (64 or 32)
    constexpr int MI = WM / 16;       // 4 or 2

    __shared__ __align__(16) __hip_bfloat16 As[BM * 64];
    __shared__ __align__(16) __hip_bfloat16 Bs[128 * 64];

    const int tid  = threadIdx.x;
    const int lane = tid & 63;
    const int wid  = tid >> 6;
    const int wm   = (wid >> 1) * WM;
    const int wn   = (wid & 1) * 64;
    const int bm   = blockIdx.y * BM;
    const int bn   = blockIdx.x * 128;

    const int srow8 = lane >> 3;
    const int sslot = (lane & 7) ^ srow8;
    const int r = lane & 15;
    const int g = lane >> 4;

    f32x4 acc[MI][4] = {};

    for (int k0 = 0; k0 < KD; k0 += 64) {
        #pragma unroll
        for (int p = 0; p < BM / 32; ++p) {
            const int rowA = p * 32 + wid * 8 + srow8;
            gload16(&A[(size_t)(bm + rowA) * KD + k0 + sslot * 8],
                    (char*)As + (p * 32 + wid * 8) * 128);
        }
        #pragma unroll
        for (int p = 0; p < 4; ++p) {
            const int rowB = p * 32 + wid * 8 + srow8;
            gload16(&Bt[(size_t)(bn + rowB) * KD + k0 + sslot * 8],
                    (char*)Bs + (p * 32 + wid * 8) * 128);
        }
        __syncthreads();

        bf16x8 af[2][MI], bfr[2][4];
        #pragma unroll
        for (int s = 0; s < 2; ++s) {
            const int physA = (s * 4 + g) ^ (r & 7);
            #pragma unroll
            for (int mi = 0; mi < MI; ++mi)
                af[s][mi] = *(const bf16x8*)((const char*)As + (wm + mi * 16 + r) * 128 + physA * 16);
            #pragma unroll
            for (int ni = 0; ni < 4; ++ni)
                bfr[s][ni] = *(const bf16x8*)((const char*)Bs + (wn + ni * 16 + r) * 128 + physA * 16);
        }
        #pragma unroll
        for (int s = 0; s < 2; ++s)
            #pragma unroll
            for (int mi = 0; mi < MI; ++mi)
                #pragma unroll
                for (int ni = 0; ni < 4; ++ni)
                    acc[mi][ni] = __builtin_amdgcn_mfma_f32_16x16x32_bf16(
                        af[s][mi], bfr[s][ni], acc[mi][ni], 0, 0, 0);
        __syncthreads();
    }

    #pragma unroll
    for (int ni = 0; ni < 4; ++ni) {
        const int col = bn + wn + ni * 16 + r;
        const float* bsel = (col < 256) ? b0 : (col < 512 ? b1 : b2);
        const float bias = bsel[col & 255];
        #pragma unroll
        for (int mi = 0; mi < MI; ++mi) {
            #pragma unroll
            for (int q = 0; q < 4; ++q) {
                const int row = bm + wm + mi * 16 + g * 4 + q;
                float v = acc[mi][ni][q] + bias;
                if (RES)  v += __bfloat162float(res[(size_t)row * N + col]);
                if (LRELU) v = v > 0.f ? v : 0.01f * v;
                if (OUTT == 0)      ((float*)Cout)[(size_t)row * N + col] = v;
                else if (OUTT == 1) ((__hip_bfloat16*)Cout)[(size_t)row * N + col] = __float2bfloat16(v);
                else                ((_Float16*)Cout)[(size_t)row * N + col] = (_Float16)v;
            }
        }
    }
}

// ---------------------------------------------------------------------------
// prep: weights fp32[K][N] -> bf16[N][K]; features -> bf16; Wp/bp -> f16 rows.
// ---------------------------------------------------------------------------
__global__ __launch_bounds__(256) void prep_kernel(
    const float* __restrict__ W_in, const float* __restrict__ Wq,
    const float* __restrict__ Wk,  const float* __restrict__ Wv,
    const float* __restrict__ Wo,  const float* __restrict__ W_out,
    const float* __restrict__ features,
    const float* __restrict__ Wp,  const float* __restrict__ bp,
    __hip_bfloat16* __restrict__ WtIn,  __hip_bfloat16* __restrict__ WtQKV,
    __hip_bfloat16* __restrict__ WtO,   __hip_bfloat16* __restrict__ WtOut,
    __hip_bfloat16* __restrict__ featb, _Float16* __restrict__ Wpb)
{
    const int b = blockIdx.x;
    if (b < 592) {
        const float* srcs[10] = {W_in, Wq, Wk, Wv, Wq + 65536, Wk + 65536,
                                 Wv + 65536, Wo, Wo + 65536, W_out};
        __hip_bfloat16* dsts[10] = {
            WtIn, WtQKV, WtQKV + 65536, WtQKV + 131072,
            WtQKV + 196608, WtQKV + 262144, WtQKV + 327680,
            WtO, WtO + 65536, WtOut};
        const int Ks[10]    = {64,256,256,256,256,256,256,256,256,256};
        const int start[10] = {0,16,80,144,208,272,336,400,464,528};
        int j = 0;
        #pragma unroll
        for (int i = 1; i < 10; ++i) if (b >= start[i]) j = i;
        const int t  = b - start[j];
        const int Kd = Ks[j];
        const int ntk = Kd >> 5;
        const int tn = t / ntk;
        const int tk = t - tn * ntk;

        __shared__ float s[32][33];
        const int tx = threadIdx.x & 31, ty = threadIdx.x >> 5;
        const float* src = srcs[j];
        #pragma unroll
        for (int i = 0; i < 4; ++i)
            s[ty + i * 8][tx] = src[(size_t)(tk * 32 + ty + i * 8) * 256 + tn * 32 + tx];
        __syncthreads();
        __hip_bfloat16* dst = dsts[j];
        #pragma unroll
        for (int i = 0; i < 4; ++i)
            dst[(size_t)(tn * 32 + ty + i * 8) * Kd + tk * 32 + tx] =
                __float2bfloat16(s[tx][ty + i * 8]);
    } else if (b < 1616) {
        const int i = (b - 592) * 1024 + threadIdx.x * 4;
        const float4 v = *(const float4*)&features[i];
        __hip_bfloat16 tmp[4] = {__float2bfloat16(v.x), __float2bfloat16(v.y),
                                 __float2bfloat16(v.z), __float2bfloat16(v.w)};
        *(uint2*)&featb[i] = *(const uint2*)tmp;
    } else {
        // Wp (L,3,256) + bp (L,256) -> Wpb[l][4][256] f16 (row 3 = bp)
        const int e8 = threadIdx.x * 8;
        const int l  = e8 >> 10;
        const int rr = (e8 >> 8) & 3;
        const int c  = e8 & 255;
        const float* src = (rr < 3) ? (Wp + (size_t)l * 768 + rr * 256 + c)
                                    : (bp + (size_t)l * 256 + c);
        const float4 f0 = ((const float4*)src)[0];
        const float4 f1 = ((const float4*)src)[1];
        _Float16 t[8] = {(_Float16)f0.x, (_Float16)f0.y, (_Float16)f0.z, (_Float16)f0.w,
                         (_Float16)f1.x, (_Float16)f1.y, (_Float16)f1.z, (_Float16)f1.w};
        *(uint4*)&Wpb[(size_t)l * 1024 + rr * 256 + c] = *(const uint4*)t;
    }
}

// ---------------------------------------------------------------------------
// KNN attention (round-8 version, measured-equal best): f16 qkv, folded
// pos-encoding, tr-read PV, 2 pts / 256 threads.
// ---------------------------------------------------------------------------
__global__ __launch_bounds__(256) void knn_attn_kernel(
    const float* __restrict__ xyz,        // [BPTS,3]
    const int*   __restrict__ idx,        // [BPTS,KNN]
    const _Float16* __restrict__ qkv,     // [BPTS,768] = q|k|v
    const _Float16* __restrict__ Wpb,     // [4][256]  (Wp rows + bp)
    __hip_bfloat16* __restrict__ o)       // [BPTS,256]
{
    const int tid = threadIdx.x;
    const int pt  = tid >> 7;
    const int lt  = tid & 127;
    const int p0  = blockIdx.x * 2;
    const int p   = p0 + pt;
    const int hh  = lt >> 4;
    const int k   = lt & 15;

    __shared__ float s_rel[2][KNN][3];
    __shared__ float s_wq[2][8][4];
    __shared__ _Float16 s_ah[2][8][KNN];                 // attn weights, f16
    __shared__ float s_arel[2][8][3];
    __shared__ __align__(16) char v_raw[16384];          // V subtiled, 2x8KB

    // --- QK loads (oldest in flight) ---
    const int jrow = ((p >> 13) << 13) + idx[p * KNN + k];
    const h8* qp = (const h8*)(qkv + (size_t)p * 768 + hh * 32);
    const h8* kp = (const h8*)(qkv + (size_t)jrow * 768 + 256 + hh * 32);
    const h8 q0 = qp[0], q1 = qp[1];
    const h8 k0 = kp[0], k1 = kp[1];

    // --- V reg staging: thread owns row sk, 4x16B chunks ---
    const int sk = lt >> 3;                  // 0..15 neighbor row
    const int c4 = lt & 7;
    const int jr_st = ((p >> 13) << 13) + idx[p * KNN + sk];
    const uint4* vsrc = (const uint4*)(qkv + (size_t)jr_st * 768 + 512 + c4 * 8);
    const uint4 st0 = vsrc[0];
    const uint4 st1 = vsrc[8];
    const uint4 st2 = vsrc[16];
    const uint4 st3 = vsrc[24];
    const int dbase = pt * 8192 + (sk >> 2) * 2048 + (c4 >> 1) * 128
                    + (sk & 3) * 32 + (c4 & 1) * 16;

    // --- side computations while loads fly ---
    if (tid < 32) {
        const int pp = tid >> 4, kk = tid & 15;
        const int pg = p0 + pp;
        const int jr = ((pg >> 13) << 13) + idx[pg * KNN + kk];
        s_rel[pp][kk][0] = xyz[pg * 3 + 0] - xyz[jr * 3 + 0];
        s_rel[pp][kk][1] = xyz[pg * 3 + 1] - xyz[jr * 3 + 1];
        s_rel[pp][kk][2] = xyz[pg * 3 + 2] - xyz[jr * 3 + 2];
    } else if (tid < 96) {
        const int t2 = tid - 32;
        const int pp = t2 >> 5, hq = (t2 >> 2) & 7, j = t2 & 3;
        const h8* qr = (const h8*)(qkv + (size_t)(p0 + pp) * 768 + hq * 32);
        const h8* wr = (const h8*)(Wpb + j * 256 + hq * 32);
        const h8 a0 = qr[0], a1 = qr[1], b0 = wr[0], b1 = wr[1];
        float acc = 0.f;
        #pragma unroll
        for (int i = 0; i < 4; ++i)
            acc = __builtin_amdgcn_fdot2(((const h2*)&a0)[i], ((const h2*)&b0)[i], acc, false);
        #pragma unroll
        for (int i = 0; i < 4; ++i)
            acc = __builtin_amdgcn_fdot2(((const h2*)&a1)[i], ((const h2*)&b1)[i], acc, false);
        s_wq[pp][hq][j] = acc;
    }

    // --- QK dot (fdot2) ---
    float dot = 0.f;
    #pragma unroll
    for (int i = 0; i < 4; ++i)
        dot = __builtin_amdgcn_fdot2(((const h2*)&q0)[i], ((const h2*)&k0)[i], dot, false);
    #pragma unroll
    for (int i = 0; i < 4; ++i)
        dot = __builtin_amdgcn_fdot2(((const h2*)&q1)[i], ((const h2*)&k1)[i], dot, false);
    __syncthreads();

    // --- logit + softmax + arel ---
    const float r0 = s_rel[pt][k][0], r1 = s_rel[pt][k][1], r2 = s_rel[pt][k][2];
    const float logit = (dot + r0 * s_wq[pt][hh][0] + r1 * s_wq[pt][hh][1]
                             + r2 * s_wq[pt][hh][2] + s_wq[pt][hh][3])
                        * 0.1767766952966369f;
    float mx = logit;
    #pragma unroll
    for (int off = 8; off >= 1; off >>= 1)
        mx = fmaxf(mx, __shfl_xor(mx, off, 16));
    const float e = __expf(logit - mx);
    float den = e;
    #pragma unroll
    for (int off = 8; off >= 1; off >>= 1)
        den += __shfl_xor(den, off, 16);
    const float attn = e / den;
    s_ah[pt][hh][k] = (_Float16)attn;

    float a0 = attn * r0, a1 = attn * r1, a2 = attn * r2;
    #pragma unroll
    for (int off = 8; off >= 1; off >>= 1) {
        a0 += __shfl_xor(a0, off, 16);
        a1 += __shfl_xor(a1, off, 16);
        a2 += __shfl_xor(a2, off, 16);
    }
    if (k == 0) {
        s_arel[pt][hh][0] = a0;
        s_arel[pt][hh][1] = a1;
        s_arel[pt][hh][2] = a2;
    }

    // --- V staging LDS writes ---
    *(uint4*)(v_raw + dbase +    0) = st0;
    *(uint4*)(v_raw + dbase +  512) = st1;
    *(uint4*)(v_raw + dbase + 1024) = st2;
    *(uint4*)(v_raw + dbase + 1536) = st3;
    __syncthreads();

    // --- PV via hardware transpose reads ---
    {
        const int w   = tid >> 6;          // wave 0..3
        const int l   = tid & 63;
        const int pt2 = w >> 1;
        const int H   = w & 1;             // ch half (128)
        const int g   = l >> 4;
        const int li  = l & 15;
        const int chA = H * 128 + g * 16 + li;
        const int chB = chA + 64;
        const int hA  = chA >> 5, hB = chB >> 5;
        const int p2  = p0 + pt2;

        const unsigned vg = (unsigned)(size_t)
            (__attribute__((address_space(3))) char*)(v_raw + pt2 * 8192 + H * 1024 + l * 8);

        uint2 rA0, rA1, rA2, rA3, rB0, rB1, rB2, rB3;
        asm volatile("ds_read_b64_tr_b16 %0, %1 offset:0"    : "=v"(rA0) : "v"(vg));
        asm volatile("ds_read_b64_tr_b16 %0, %1 offset:2048" : "=v"(rA1) : "v"(vg));
        asm volatile("ds_read_b64_tr_b16 %0, %1 offset:4096" : "=v"(rA2) : "v"(vg));
        asm volatile("ds_read_b64_tr_b16 %0, %1 offset:6144" : "=v"(rA3) : "v"(vg));
        asm volatile("ds_read_b64_tr_b16 %0, %1 offset:512"  : "=v"(rB0) : "v"(vg));
        asm volatile("ds_read_b64_tr_b16 %0, %1 offset:2560" : "=v"(rB1) : "v"(vg));
        asm volatile("ds_read_b64_tr_b16 %0, %1 offset:4608" : "=v"(rB2) : "v"(vg));
        asm volatile("ds_read_b64_tr_b16 %0, %1 offset:6656" : "=v"(rB3) : "v"(vg));
        asm volatile("s_waitcnt lgkmcnt(0)" ::: "memory");
        __builtin_amdgcn_sched_barrier(0);

        const h2* aA = (const h2*)&s_ah[pt2][hA][0];
        const h2* aB = (const h2*)&s_ah[pt2][hB][0];

        float oA = 0.f, oB = 0.f;
        #define PVKT(rr, aa, acc, kt)                                             \
            acc = __builtin_amdgcn_fdot2(aa[2*kt],   *(const h2*)&rr.x, acc, false); \
            acc = __builtin_amdgcn_fdot2(aa[2*kt+1], *(const h2*)&rr.y, acc, false);
        PVKT(rA0, aA, oA, 0) PVKT(rA1, aA, oA, 1) PVKT(rA2, aA, oA, 2) PVKT(rA3, aA, oA, 3)
        PVKT(rB0, aB, oB, 0) PVKT(rB1, aB, oB, 1) PVKT(rB2, aB, oB, 2) PVKT(rB3, aB, oB, 3)
        #undef PVKT

        const float gA0 = s_arel[pt2][hA][0], gA1 = s_arel[pt2][hA][1], gA2 = s_arel[pt2][hA][2];
        const float gB0 = s_arel[pt2][hB][0], gB1 = s_arel[pt2][hB][1], gB2 = s_arel[pt2][hB][2];
        oA += gA0 * (float)Wpb[chA] + gA1 * (float)Wpb[256 + chA]
            + gA2 * (float)Wpb[512 + chA] + (float)Wpb[768 + chA];
        oB += gB0 * (float)Wpb[chB] + gB1 * (float)Wpb[256 + chB]
            + gB2 * (float)Wpb[512 + chB] + (float)Wpb[768 + chB];
        o[(size_t)p2 * 256 + chA] = __float2bfloat16(oA);
        o[(size_t)p2 * 256 + chB] = __float2bfloat16(oB);
    }
}

// ---------------------------------------------------------------------------
extern "C" void kernel_launch(void* const* d_in, const int* in_sizes, int n_in,
                              void* d_out, int out_size, void* d_ws, size_t ws_size,
                              hipStream_t stream)
{
    const float* xyzs     = (const float*)d_in[0];
    const float* features = (const float*)d_in[1];
    const int*   k_graph  = (const int*)  d_in[2];
    const float* W_in     = (const float*)d_in[3];
    const float* b_in     = (const float*)d_in[4];
    const float* Wq       = (const float*)d_in[5];
    const float* bq       = (const float*)d_in[6];
    const float* Wk       = (const float*)d_in[7];
    const float* bk       = (const float*)d_in[8];
    const float* Wv       = (const float*)d_in[9];
    const float* bv       = (const float*)d_in[10];
    const float* Wp       = (const float*)d_in[11];
    const float* bp       = (const float*)d_in[12];
    const float* Wo       = (const float*)d_in[13];
    const float* bo       = (const float*)d_in[14];
    const float* W_out    = (const float*)d_in[15];
    const float* b_out    = (const float*)d_in[16];

    __hip_bfloat16* featb = (__hip_bfloat16*)d_ws;       // 16384*64
    __hip_bfloat16* f     = featb + 1048576;             // 16384*256
    _Float16*       qkv   = (_Float16*)(f + 4194304);    // 16384*768 (f16)
    __hip_bfloat16* ob    = (__hip_bfloat16*)(qkv + 12582912);  // 16384*256
    __hip_bfloat16* WtIn  = ob + 4194304;                // 256*64
    __hip_bfloat16* WtQKV = WtIn + 16384;                // 2*768*256
    __hip_bfloat16* WtO   = WtQKV + 393216;              // 2*256*256
    __hip_bfloat16* WtOut = WtO + 131072;                // 256*256
    _Float16*       Wpb   = (_Float16*)(WtOut + 65536);  // 2*1024

    prep_kernel<<<1617, 256, 0, stream>>>(W_in, Wq, Wk, Wv, Wo, W_out, features,
                                          Wp, bp, WtIn, WtQKV, WtO, WtOut,
                                          featb, Wpb);

    // f = features @ W_in + b_in   (BM=64 -> 512 blocks)
    gemm_mfma<64, false, 1, false, 64><<<dim3(2, 256), 256, 0, stream>>>(
        featb, WtIn, b_in, b_in, b_in, nullptr, f, BPTS, 256);

    for (int l = 0; l < 2; ++l) {
        gemm_mfma<256, false, 2, false, 128><<<dim3(6, 128), 256, 0, stream>>>(
            f, WtQKV + (size_t)l * 196608,
            bq + l * 256, bk + l * 256, bv + l * 256, nullptr, qkv, BPTS, 768);

        knn_attn_kernel<<<dim3(BPTS / 2), 256, 0, stream>>>(
            xyzs, k_graph, qkv, Wpb + (size_t)l * 1024, ob);

        // f = ob @ Wo + bo + f   (BM=64 -> 512 blocks)
        gemm_mfma<256, true, 1, false, 64><<<dim3(2, 256), 256, 0, stream>>>(
            ob, WtO + (size_t)l * 65536,
            bo + l * 256, bo + l * 256, bo + l * 256, f, f, BPTS, 256);
    }

    // out = leaky_relu(f @ W_out + b_out), fp32  (BM=64 -> 512 blocks)
    gemm_mfma<256, false, 0, true, 64><<<dim3(2, 256), 256, 0, stream>>>(
        f, WtOut, b_out, b_out, b_out, nullptr, (float*)d_out, BPTS, 256);
}